// Round 5
// baseline (643.546 us; speedup 1.0000x reference)
//
#include <hip/hip_runtime.h>
#include <cmath>

#define N      50000
#define E      800000
#define NFEAT  128
#define NHID   128
#define NCLASS 40
#define NUM_HOPS 4
#define NF     (N * NHID)   // 6,400,000 floats per h buffer
#define GR     64           // rows per block (hop kernel)
#define RPW    16           // rows per wave  (GR / 4 waves)
#define NB     ((N + 255) / 256)   // 196 scan blocks

// ---------------- CSR build ----------------

__global__ void k_hist(const int* __restrict__ row, int* __restrict__ cnt) {
    int e = blockIdx.x * blockDim.x + threadIdx.x;
    if (e < E) atomicAdd(&cnt[row[e]], 1);
}

// Phase 1: per-block (256 elems) reduction of cnt -> bsum[block]
__global__ void k_bsum(const int* __restrict__ cnt, int* __restrict__ bsum) {
    int t = threadIdx.x;
    int i = blockIdx.x * 256 + t;
    int v = (i < N) ? cnt[i] : 0;
    for (int off = 32; off; off >>= 1) v += __shfl_xor(v, off);
    __shared__ int ws[4];
    if ((t & 63) == 0) ws[t >> 6] = v;
    __syncthreads();
    if (t == 0) bsum[blockIdx.x] = ws[0] + ws[1] + ws[2] + ws[3];
}

// Phase 2: single small block scans bsum[0..NB-1] -> exclusive boff[0..NB-1]
__global__ void k_scanb(const int* __restrict__ bsum, int* __restrict__ boff) {
    __shared__ int ws[4];
    int t = threadIdx.x;
    int v = (t < NB) ? bsum[t] : 0;
    int lane = t & 63, w = t >> 6;
    int incl = v;
    for (int off = 1; off < 64; off <<= 1) {
        int u = __shfl_up(incl, off);
        if (lane >= off) incl += u;
    }
    if (lane == 63) ws[w] = incl;
    __syncthreads();
    int woff = 0;
    for (int k = 0; k < w; ++k) woff += ws[k];
    if (t < NB) boff[t] = incl - v + woff;
}

// Phase 3: in-block exclusive scan of cnt chunk + block offset -> rp; cnt becomes cursor
__global__ void k_expand(int* __restrict__ cnt, const int* __restrict__ boff,
                         int* __restrict__ rp) {
    __shared__ int ws[4];
    int t = threadIdx.x;
    int i = blockIdx.x * 256 + t;
    int c = (i < N) ? cnt[i] : 0;
    int lane = t & 63, w = t >> 6;
    int incl = c;
    for (int off = 1; off < 64; off <<= 1) {
        int u = __shfl_up(incl, off);
        if (lane >= off) incl += u;
    }
    if (lane == 63) ws[w] = incl;
    __syncthreads();
    int woff = 0;
    for (int k = 0; k < w; ++k) woff += ws[k];
    int r = boff[blockIdx.x] + incl - c + woff;   // exclusive prefix
    if (i < N) {
        rp[i]  = r;
        cnt[i] = r;           // scatter cursor
        if (i == N - 1) rp[N] = r + c;   // = E
    }
}

__global__ void k_scatter(const int* __restrict__ row, const int* __restrict__ col,
                          const float* __restrict__ val,
                          int* __restrict__ cur, int2* __restrict__ ev) {
    int e = blockIdx.x * blockDim.x + threadIdx.x;
    if (e < E) {
        int r = row[e];
        int p = atomicAdd(&cur[r], 1);
        ev[p] = make_int2(col[e], __float_as_int(val[e]));
    }
}

// ---------------- Fused hop: SpMM (into LDS) + GEMM(128x128 W) + ReLU ----------------
// Phase 1: each of 4 waves aggregates 16 rows (unroll-8 gather MLP) into the LDS tile.
// Phase 2: thread tile 8 rows x 4 cols from LDS, W streamed float4 (L2-hot).
// Edge-sum order identical to the separate spmm kernel -> bit-identical results.

__global__ __launch_bounds__(256) void k_hop(const int* __restrict__ rp,
                                             const int2* __restrict__ ev,
                                             const float* __restrict__ x,
                                             const float* __restrict__ W,
                                             float* __restrict__ y) {
    __shared__ float xl[GR * NHID];   // 32 KB
    int t = threadIdx.x;
    int lane = t & 63;
    int wv = t >> 6;                  // wave 0..3
    int rowbase = blockIdx.x * GR;

    // ---- phase 1: SpMM rows -> LDS ----
    float2* xl2 = (float2*)xl;
    for (int rr = 0; rr < RPW; ++rr) {
        int lr = wv * RPW + rr;
        int row = rowbase + lr;
        float ax = 0.f, ay = 0.f;
        if (row < N) {
            int beg = rp[row], end = rp[row + 1];
            int j = beg;
            for (; j + 8 <= end; j += 8) {
                int2 e0 = ev[j],     e1 = ev[j + 1], e2 = ev[j + 2], e3 = ev[j + 3];
                int2 e4 = ev[j + 4], e5 = ev[j + 5], e6 = ev[j + 6], e7 = ev[j + 7];
                float2 x0 = ((const float2*)(x + (size_t)e0.x * NHID))[lane];
                float2 x1 = ((const float2*)(x + (size_t)e1.x * NHID))[lane];
                float2 x2 = ((const float2*)(x + (size_t)e2.x * NHID))[lane];
                float2 x3 = ((const float2*)(x + (size_t)e3.x * NHID))[lane];
                float2 x4 = ((const float2*)(x + (size_t)e4.x * NHID))[lane];
                float2 x5 = ((const float2*)(x + (size_t)e5.x * NHID))[lane];
                float2 x6 = ((const float2*)(x + (size_t)e6.x * NHID))[lane];
                float2 x7 = ((const float2*)(x + (size_t)e7.x * NHID))[lane];
                ax = fmaf(__int_as_float(e0.y), x0.x, ax); ay = fmaf(__int_as_float(e0.y), x0.y, ay);
                ax = fmaf(__int_as_float(e1.y), x1.x, ax); ay = fmaf(__int_as_float(e1.y), x1.y, ay);
                ax = fmaf(__int_as_float(e2.y), x2.x, ax); ay = fmaf(__int_as_float(e2.y), x2.y, ay);
                ax = fmaf(__int_as_float(e3.y), x3.x, ax); ay = fmaf(__int_as_float(e3.y), x3.y, ay);
                ax = fmaf(__int_as_float(e4.y), x4.x, ax); ay = fmaf(__int_as_float(e4.y), x4.y, ay);
                ax = fmaf(__int_as_float(e5.y), x5.x, ax); ay = fmaf(__int_as_float(e5.y), x5.y, ay);
                ax = fmaf(__int_as_float(e6.y), x6.x, ax); ay = fmaf(__int_as_float(e6.y), x6.y, ay);
                ax = fmaf(__int_as_float(e7.y), x7.x, ax); ay = fmaf(__int_as_float(e7.y), x7.y, ay);
            }
            for (; j < end; ++j) {
                int2 e = ev[j];
                const float2 xv = ((const float2*)(x + (size_t)e.x * NHID))[lane];
                float v = __int_as_float(e.y);
                ax = fmaf(v, xv.x, ax);
                ay = fmaf(v, xv.y, ay);
            }
        }
        xl2[lr * 64 + lane] = make_float2(ax, ay);   // 8B stride: 2-way bank alias = free
    }
    __syncthreads();

    // ---- phase 2: GEMM + ReLU ----
    int cg = (t & 31) << 2;   // col base (4 cols)
    int rg = (t >> 5) << 3;   // row base (8 rows)
    float4 acc[8];
#pragma unroll
    for (int r = 0; r < 8; ++r) acc[r] = make_float4(0.f, 0.f, 0.f, 0.f);
    const float4* Wq = (const float4*)W;
    float4 w = Wq[cg >> 2];
    for (int k = 0; k < NHID; ++k) {
        float4 wn = (k + 1 < NHID) ? Wq[(k + 1) * (NHID / 4) + (cg >> 2)] : w;
#pragma unroll
        for (int r = 0; r < 8; ++r) {
            float xv = xl[(rg + r) * NHID + k];
            acc[r].x = fmaf(xv, w.x, acc[r].x);
            acc[r].y = fmaf(xv, w.y, acc[r].y);
            acc[r].z = fmaf(xv, w.z, acc[r].z);
            acc[r].w = fmaf(xv, w.w, acc[r].w);
        }
        w = wn;
    }
#pragma unroll
    for (int r = 0; r < 8; ++r) {
        int row = rowbase + rg + r;
        if (row < N) {
            float4 o;
            o.x = fmaxf(acc[r].x, 0.f);
            o.y = fmaxf(acc[r].y, 0.f);
            o.z = fmaxf(acc[r].z, 0.f);
            o.w = fmaxf(acc[r].w, 0.f);
            *(float4*)(y + (size_t)row * NHID + cg) = o;
        }
    }
}

// ---------------- Fused attention + output head (one wave per node) ----------------

__global__ void k_attn_final(const float* __restrict__ f, const float* __restrict__ hb,
                             const float* __restrict__ att_w, const float* __restrict__ att_b,
                             const float* __restrict__ fc_w, const float* __restrict__ fc_b,
                             float* __restrict__ out) {
    __shared__ float xs[4][NHID];
    int wslot = threadIdx.x >> 6;
    int node  = blockIdx.x * 4 + wslot;
    int lane  = threadIdx.x & 63;
    if (node < N) {
        const float2 whv = ((const float2*)att_w)[lane];
        const float2 wfv = ((const float2*)(att_w + NHID))[lane];
        const float2 fv  = ((const float2*)(f + (size_t)node * NFEAT))[lane];
        const float2 h0 = ((const float2*)(hb + 0 * (size_t)NF + (size_t)node * NHID))[lane];
        const float2 h1 = ((const float2*)(hb + 1 * (size_t)NF + (size_t)node * NHID))[lane];
        const float2 h2 = ((const float2*)(hb + 2 * (size_t)NF + (size_t)node * NHID))[lane];
        const float2 h3 = ((const float2*)(hb + 3 * (size_t)NF + (size_t)node * NHID))[lane];
        float s0 = h0.x * whv.x + h0.y * whv.y;
        float s1 = h1.x * whv.x + h1.y * whv.y;
        float s2 = h2.x * whv.x + h2.y * whv.y;
        float s3 = h3.x * whv.x + h3.y * whv.y;
        float s4 = fv.x * wfv.x + fv.y * wfv.y;
        for (int off = 32; off; off >>= 1) {
            s0 += __shfl_xor(s0, off);
            s1 += __shfl_xor(s1, off);
            s2 += __shfl_xor(s2, off);
            s3 += __shfl_xor(s3, off);
            s4 += __shfl_xor(s4, off);
        }
        float b = att_b[0];
        float g0 = 1.f / (1.f + __expf(-(s0 + s4 + b)));
        float g1 = 1.f / (1.f + __expf(-(s1 + s4 + b)));
        float g2 = 1.f / (1.f + __expf(-(s2 + s4 + b)));
        float g3 = 1.f / (1.f + __expf(-(s3 + s4 + b)));
        float m = fmaxf(fmaxf(g0, g1), fmaxf(g2, g3));
        float e0 = __expf(g0 - m), e1 = __expf(g1 - m), e2 = __expf(g2 - m), e3 = __expf(g3 - m);
        float inv = 1.f / (e0 + e1 + e2 + e3);
        float w0 = e0 * inv, w1 = e1 * inv, w2 = e2 * inv, w3 = e3 * inv;
        float ax = w0 * h0.x + w1 * h1.x + w2 * h2.x + w3 * h3.x;
        float ay = w0 * h0.y + w1 * h1.y + w2 * h2.y + w3 * h3.y;
        xs[wslot][2 * lane]     = ax;
        xs[wslot][2 * lane + 1] = ay;
    }
    __syncthreads();
    if (node < N) {
        float logit = 0.f;
        if (lane < NCLASS) {
            logit = fc_b[lane];
            const float4* xs4 = (const float4*)xs[wslot];
#pragma unroll
            for (int k4 = 0; k4 < NHID / 4; ++k4) {   // 32 ds_read_b128 instead of 128 b32
                float4 xv = xs4[k4];
                int k = k4 << 2;
                logit = fmaf(xv.x, fc_w[(k + 0) * NCLASS + lane], logit);
                logit = fmaf(xv.y, fc_w[(k + 1) * NCLASS + lane], logit);
                logit = fmaf(xv.z, fc_w[(k + 2) * NCLASS + lane], logit);
                logit = fmaf(xv.w, fc_w[(k + 3) * NCLASS + lane], logit);
            }
        }
        float mv = (lane < NCLASS) ? logit : -INFINITY;
        for (int off = 32; off; off >>= 1) mv = fmaxf(mv, __shfl_xor(mv, off));
        float ev = (lane < NCLASS) ? __expf(logit - mv) : 0.f;
        float sum = ev;
        for (int off = 32; off; off >>= 1) sum += __shfl_xor(sum, off);
        if (lane < NCLASS)
            out[(size_t)node * NCLASS + lane] = logit - mv - logf(sum);
    }
}

// ---------------- launch ----------------

extern "C" void kernel_launch(void* const* d_in, const int* in_sizes, int n_in,
                              void* d_out, int out_size, void* d_ws, size_t ws_size,
                              hipStream_t stream) {
    const float* features = (const float*)d_in[0];
    const int*   erow     = (const int*)d_in[1];
    const int*   ecol     = (const int*)d_in[2];
    const float* eval_    = (const float*)d_in[3];
    const float* Wg       = (const float*)d_in[4];
    const float* att_w    = (const float*)d_in[5];
    const float* att_b    = (const float*)d_in[6];
    const float* fc_w     = (const float*)d_in[7];
    const float* fc_b     = (const float*)d_in[8];
    float*       out      = (float*)d_out;

    // workspace layout (float-size slots; ~110 MB total)
    float* hb   = (float*)d_ws;                // 4*NF   : h1..h4
    int2*  ev   = (int2*)(hb + 4 * (size_t)NF);// E int2 : packed (col, val)
    int*   rp   = (int*)(ev + E);              // N+1 (+pad)
    int*   cnt  = rp + (N + 4);                // N      : histogram / cursor
    int*   bsum = cnt + N;                     // NB     : block sums
    int*   boff = bsum + NB;                   // NB     : block offsets

    // CSR build
    hipMemsetAsync(cnt, 0, N * sizeof(int), stream);
    k_hist<<<(E + 255) / 256, 256, 0, stream>>>(erow, cnt);
    k_bsum<<<NB, 256, 0, stream>>>(cnt, bsum);
    k_scanb<<<1, 256, 0, stream>>>(bsum, boff);
    k_expand<<<NB, 256, 0, stream>>>(cnt, boff, rp);
    k_scatter<<<(E + 255) / 256, 256, 0, stream>>>(erow, ecol, eval_, cnt, ev);

    // hops (fused spmm+gemm)
    const float* hprev = features;
    for (int i = 0; i < NUM_HOPS; ++i) {
        k_hop<<<(N + GR - 1) / GR, 256, 0, stream>>>(rp, ev, hprev,
                                                     Wg + (size_t)i * NHID * NHID,
                                                     hb + (size_t)i * NF);
        hprev = hb + (size_t)i * NF;
    }

    // fused attention + fc + log_softmax
    k_attn_final<<<(N + 3) / 4, 256, 0, stream>>>(features, hb, att_w, att_b, fc_w, fc_b, out);
}

// Round 6
// 573.577 us; speedup vs baseline: 1.1220x; 1.1220x over previous
//
#include <hip/hip_runtime.h>
#include <cmath>

#define N      50000
#define E      800000
#define NFEAT  128
#define NHID   128
#define NCLASS 40
#define NUM_HOPS 4
#define NF     (N * NHID)   // 6,400,000 floats per h buffer
#define GR     64           // GEMM rows per block
#define NB     ((N + 255) / 256)   // 196 scan blocks
#define EVCAP  (E + 8 * N)  // padded edge-array capacity

// ---------------- CSR build (rows padded to multiple of 8 edges) ----------------

__global__ void k_hist(const int* __restrict__ row, int* __restrict__ cnt) {
    int e = blockIdx.x * blockDim.x + threadIdx.x;
    if (e < E) atomicAdd(&cnt[row[e]], 1);
}

// Phase 1: per-block (256 elems) reduction of PADDED counts -> bsum[block]
__global__ void k_bsum(const int* __restrict__ cnt, int* __restrict__ bsum) {
    int t = threadIdx.x;
    int i = blockIdx.x * 256 + t;
    int v = (i < N) ? ((cnt[i] + 7) & ~7) : 0;
    for (int off = 32; off; off >>= 1) v += __shfl_xor(v, off);
    __shared__ int ws[4];
    if ((t & 63) == 0) ws[t >> 6] = v;
    __syncthreads();
    if (t == 0) bsum[blockIdx.x] = ws[0] + ws[1] + ws[2] + ws[3];
}

// Phase 2: single small block scans bsum[0..NB-1] -> exclusive boff[0..NB-1]
__global__ void k_scanb(const int* __restrict__ bsum, int* __restrict__ boff) {
    __shared__ int ws[4];
    int t = threadIdx.x;
    int v = (t < NB) ? bsum[t] : 0;
    int lane = t & 63, w = t >> 6;
    int incl = v;
    for (int off = 1; off < 64; off <<= 1) {
        int u = __shfl_up(incl, off);
        if (lane >= off) incl += u;
    }
    if (lane == 63) ws[w] = incl;
    __syncthreads();
    int woff = 0;
    for (int k = 0; k < w; ++k) woff += ws[k];
    if (t < NB) boff[t] = incl - v + woff;
}

// Phase 3: in-block exclusive scan of padded counts + block offset -> rp; cnt becomes cursor
__global__ void k_expand(int* __restrict__ cnt, const int* __restrict__ boff,
                         int* __restrict__ rp) {
    __shared__ int ws[4];
    int t = threadIdx.x;
    int i = blockIdx.x * 256 + t;
    int pc = (i < N) ? ((cnt[i] + 7) & ~7) : 0;
    int lane = t & 63, w = t >> 6;
    int incl = pc;
    for (int off = 1; off < 64; off <<= 1) {
        int u = __shfl_up(incl, off);
        if (lane >= off) incl += u;
    }
    if (lane == 63) ws[w] = incl;
    __syncthreads();
    int woff = 0;
    for (int k = 0; k < w; ++k) woff += ws[k];
    int r = boff[blockIdx.x] + incl - pc + woff;   // exclusive prefix (padded)
    if (i < N) {
        rp[i]  = r;
        cnt[i] = r;                    // scatter cursor (real edges fill segment head)
        if (i == N - 1) rp[N] = r + pc;
    }
}

__global__ void k_scatter(const int* __restrict__ row, const int* __restrict__ col,
                          const float* __restrict__ val,
                          int* __restrict__ cur, int2* __restrict__ ev) {
    int e = blockIdx.x * blockDim.x + threadIdx.x;
    if (e < E) {
        int r = row[e];
        int p = atomicAdd(&cur[r], 1);
        ev[p] = make_int2(col[e], __float_as_int(val[e]));
    }
}

// ---------------- SpMM: y[row] = sum_j val_j * x[col_j]  (one wave per row) ----------------
// Rows padded to multiple of 8 (col=0,val=0 -> exact, x[0] stays L1-hot): the loop is
// branchless unroll-8, 8 independent 512 B gathers in flight, no serial tail.

__global__ void k_spmm(const int* __restrict__ rp, const int2* __restrict__ ev,
                       const float* __restrict__ x, float* __restrict__ y) {
    int wid  = (blockIdx.x * blockDim.x + threadIdx.x) >> 6;   // global wave id = row
    if (wid >= N) return;
    int lane = threadIdx.x & 63;
    int beg = rp[wid], end = rp[wid + 1];   // end-beg always multiple of 8
    float ax = 0.f, ay = 0.f;
    for (int j = beg; j < end; j += 8) {
        int2 e0 = ev[j],     e1 = ev[j + 1], e2 = ev[j + 2], e3 = ev[j + 3];
        int2 e4 = ev[j + 4], e5 = ev[j + 5], e6 = ev[j + 6], e7 = ev[j + 7];
        float2 x0 = ((const float2*)(x + (size_t)e0.x * NHID))[lane];
        float2 x1 = ((const float2*)(x + (size_t)e1.x * NHID))[lane];
        float2 x2 = ((const float2*)(x + (size_t)e2.x * NHID))[lane];
        float2 x3 = ((const float2*)(x + (size_t)e3.x * NHID))[lane];
        float2 x4 = ((const float2*)(x + (size_t)e4.x * NHID))[lane];
        float2 x5 = ((const float2*)(x + (size_t)e5.x * NHID))[lane];
        float2 x6 = ((const float2*)(x + (size_t)e6.x * NHID))[lane];
        float2 x7 = ((const float2*)(x + (size_t)e7.x * NHID))[lane];
        ax = fmaf(__int_as_float(e0.y), x0.x, ax); ay = fmaf(__int_as_float(e0.y), x0.y, ay);
        ax = fmaf(__int_as_float(e1.y), x1.x, ax); ay = fmaf(__int_as_float(e1.y), x1.y, ay);
        ax = fmaf(__int_as_float(e2.y), x2.x, ax); ay = fmaf(__int_as_float(e2.y), x2.y, ay);
        ax = fmaf(__int_as_float(e3.y), x3.x, ax); ay = fmaf(__int_as_float(e3.y), x3.y, ay);
        ax = fmaf(__int_as_float(e4.y), x4.x, ax); ay = fmaf(__int_as_float(e4.y), x4.y, ay);
        ax = fmaf(__int_as_float(e5.y), x5.x, ax); ay = fmaf(__int_as_float(e5.y), x5.y, ay);
        ax = fmaf(__int_as_float(e6.y), x6.x, ax); ay = fmaf(__int_as_float(e6.y), x6.y, ay);
        ax = fmaf(__int_as_float(e7.y), x7.x, ax); ay = fmaf(__int_as_float(e7.y), x7.y, ay);
    }
    float2 o; o.x = ax; o.y = ay;
    ((float2*)(y + (size_t)wid * NHID))[lane] = o;
}

// ---------------- GEMM (128x128 W) + ReLU ----------------
// 64 rows/block, 256 threads, thread tile 8 rows x 4 cols. x tile in LDS, read as
// ds_read_b128 (k blocked by 4, broadcast within wave). W streamed float4 (L2-hot).
// FMA order over k identical to scalar version -> bit-identical.

__global__ __launch_bounds__(256) void k_gemm_relu(const float* __restrict__ x,
                                                   const float* __restrict__ W,
                                                   float* __restrict__ y) {
    __shared__ float xl[GR * NHID];
    int t = threadIdx.x;
    int rowbase = blockIdx.x * GR;
    int nrows = N - rowbase; if (nrows > GR) nrows = GR;
    {
        float4* xl4 = (float4*)xl;
        const float4* xg4 = (const float4*)(x + (size_t)rowbase * NHID);
        int maxq = nrows * (NHID / 4);
#pragma unroll
        for (int i = 0; i < (GR * NHID / 4) / 256; ++i) {   // 8 iters
            int idx = i * 256 + t;
            if (idx < maxq) xl4[idx] = xg4[idx];
        }
    }
    __syncthreads();
    int cq = t & 31;          // col quad (4 cols)
    int rg = (t >> 5) << 3;   // row base (8 rows)
    float4 acc[8];
#pragma unroll
    for (int r = 0; r < 8; ++r) acc[r] = make_float4(0.f, 0.f, 0.f, 0.f);
    const float4* Wq = (const float4*)W;
    for (int k4 = 0; k4 < NHID / 4; ++k4) {
        float4 w0 = Wq[(4 * k4 + 0) * (NHID / 4) + cq];
        float4 w1 = Wq[(4 * k4 + 1) * (NHID / 4) + cq];
        float4 w2 = Wq[(4 * k4 + 2) * (NHID / 4) + cq];
        float4 w3 = Wq[(4 * k4 + 3) * (NHID / 4) + cq];
#pragma unroll
        for (int r = 0; r < 8; ++r) {
            float4 xv = *(const float4*)&xl[(rg + r) * NHID + 4 * k4];  // b128 broadcast
            acc[r].x = fmaf(xv.x, w0.x, acc[r].x);
            acc[r].y = fmaf(xv.x, w0.y, acc[r].y);
            acc[r].z = fmaf(xv.x, w0.z, acc[r].z);
            acc[r].w = fmaf(xv.x, w0.w, acc[r].w);
            acc[r].x = fmaf(xv.y, w1.x, acc[r].x);
            acc[r].y = fmaf(xv.y, w1.y, acc[r].y);
            acc[r].z = fmaf(xv.y, w1.z, acc[r].z);
            acc[r].w = fmaf(xv.y, w1.w, acc[r].w);
            acc[r].x = fmaf(xv.z, w2.x, acc[r].x);
            acc[r].y = fmaf(xv.z, w2.y, acc[r].y);
            acc[r].z = fmaf(xv.z, w2.z, acc[r].z);
            acc[r].w = fmaf(xv.z, w2.w, acc[r].w);
            acc[r].x = fmaf(xv.w, w3.x, acc[r].x);
            acc[r].y = fmaf(xv.w, w3.y, acc[r].y);
            acc[r].z = fmaf(xv.w, w3.z, acc[r].z);
            acc[r].w = fmaf(xv.w, w3.w, acc[r].w);
        }
    }
#pragma unroll
    for (int r = 0; r < 8; ++r) {
        int row = rowbase + rg + r;
        if (row < N) {
            float4 o;
            o.x = fmaxf(acc[r].x, 0.f);
            o.y = fmaxf(acc[r].y, 0.f);
            o.z = fmaxf(acc[r].z, 0.f);
            o.w = fmaxf(acc[r].w, 0.f);
            *(float4*)(y + (size_t)row * NHID + (cq << 2)) = o;
        }
    }
}

// ---------------- Fused attention + output head (one wave per node) ----------------

__global__ void k_attn_final(const float* __restrict__ f, const float* __restrict__ hb,
                             const float* __restrict__ att_w, const float* __restrict__ att_b,
                             const float* __restrict__ fc_w, const float* __restrict__ fc_b,
                             float* __restrict__ out) {
    __shared__ float xs[4][NHID];
    int wslot = threadIdx.x >> 6;
    int node  = blockIdx.x * 4 + wslot;
    int lane  = threadIdx.x & 63;
    if (node < N) {
        const float2 whv = ((const float2*)att_w)[lane];
        const float2 wfv = ((const float2*)(att_w + NHID))[lane];
        const float2 fv  = ((const float2*)(f + (size_t)node * NFEAT))[lane];
        const float2 h0 = ((const float2*)(hb + 0 * (size_t)NF + (size_t)node * NHID))[lane];
        const float2 h1 = ((const float2*)(hb + 1 * (size_t)NF + (size_t)node * NHID))[lane];
        const float2 h2 = ((const float2*)(hb + 2 * (size_t)NF + (size_t)node * NHID))[lane];
        const float2 h3 = ((const float2*)(hb + 3 * (size_t)NF + (size_t)node * NHID))[lane];
        float s0 = h0.x * whv.x + h0.y * whv.y;
        float s1 = h1.x * whv.x + h1.y * whv.y;
        float s2 = h2.x * whv.x + h2.y * whv.y;
        float s3 = h3.x * whv.x + h3.y * whv.y;
        float s4 = fv.x * wfv.x + fv.y * wfv.y;
        for (int off = 32; off; off >>= 1) {
            s0 += __shfl_xor(s0, off);
            s1 += __shfl_xor(s1, off);
            s2 += __shfl_xor(s2, off);
            s3 += __shfl_xor(s3, off);
            s4 += __shfl_xor(s4, off);
        }
        float b = att_b[0];
        float g0 = 1.f / (1.f + __expf(-(s0 + s4 + b)));
        float g1 = 1.f / (1.f + __expf(-(s1 + s4 + b)));
        float g2 = 1.f / (1.f + __expf(-(s2 + s4 + b)));
        float g3 = 1.f / (1.f + __expf(-(s3 + s4 + b)));
        float m = fmaxf(fmaxf(g0, g1), fmaxf(g2, g3));
        float e0 = __expf(g0 - m), e1 = __expf(g1 - m), e2 = __expf(g2 - m), e3 = __expf(g3 - m);
        float inv = 1.f / (e0 + e1 + e2 + e3);
        float w0 = e0 * inv, w1 = e1 * inv, w2 = e2 * inv, w3 = e3 * inv;
        float ax = w0 * h0.x + w1 * h1.x + w2 * h2.x + w3 * h3.x;
        float ay = w0 * h0.y + w1 * h1.y + w2 * h2.y + w3 * h3.y;
        xs[wslot][2 * lane]     = ax;
        xs[wslot][2 * lane + 1] = ay;
    }
    __syncthreads();
    if (node < N) {
        float logit = 0.f;
        if (lane < NCLASS) {
            logit = fc_b[lane];
            const float4* xs4 = (const float4*)xs[wslot];
#pragma unroll
            for (int k4 = 0; k4 < NHID / 4; ++k4) {   // 32 ds_read_b128 instead of 128 b32
                float4 xv = xs4[k4];
                int k = k4 << 2;
                logit = fmaf(xv.x, fc_w[(k + 0) * NCLASS + lane], logit);
                logit = fmaf(xv.y, fc_w[(k + 1) * NCLASS + lane], logit);
                logit = fmaf(xv.z, fc_w[(k + 2) * NCLASS + lane], logit);
                logit = fmaf(xv.w, fc_w[(k + 3) * NCLASS + lane], logit);
            }
        }
        float mv = (lane < NCLASS) ? logit : -INFINITY;
        for (int off = 32; off; off >>= 1) mv = fmaxf(mv, __shfl_xor(mv, off));
        float ev = (lane < NCLASS) ? __expf(logit - mv) : 0.f;
        float sum = ev;
        for (int off = 32; off; off >>= 1) sum += __shfl_xor(sum, off);
        if (lane < NCLASS)
            out[(size_t)node * NCLASS + lane] = logit - mv - logf(sum);
    }
}

// ---------------- launch ----------------

extern "C" void kernel_launch(void* const* d_in, const int* in_sizes, int n_in,
                              void* d_out, int out_size, void* d_ws, size_t ws_size,
                              hipStream_t stream) {
    const float* features = (const float*)d_in[0];
    const int*   erow     = (const int*)d_in[1];
    const int*   ecol     = (const int*)d_in[2];
    const float* eval_    = (const float*)d_in[3];
    const float* Wg       = (const float*)d_in[4];
    const float* att_w    = (const float*)d_in[5];
    const float* att_b    = (const float*)d_in[6];
    const float* fc_w     = (const float*)d_in[7];
    const float* fc_b     = (const float*)d_in[8];
    float*       out      = (float*)d_out;

    // workspace layout (float-size slots; ~140 MB total)
    float* hb   = (float*)d_ws;                 // 4*NF    : h1..h4
    float* tmp  = hb + 4 * (size_t)NF;          // NF      : spmm result
    int2*  ev   = (int2*)(tmp + NF);            // EVCAP   : packed (col, val), padded rows
    int*   rp   = (int*)(ev + EVCAP);           // N+1 (+pad)
    int*   cnt  = rp + (N + 4);                 // N       : histogram / cursor
    int*   bsum = cnt + N;                      // NB      : block sums
    int*   boff = bsum + NB;                    // NB      : block offsets

    // CSR build (rows padded to x8 with col=0,val=0)
    hipMemsetAsync(cnt, 0, N * sizeof(int), stream);
    hipMemsetAsync(ev, 0, EVCAP * sizeof(int2), stream);
    k_hist<<<(E + 255) / 256, 256, 0, stream>>>(erow, cnt);
    k_bsum<<<NB, 256, 0, stream>>>(cnt, bsum);
    k_scanb<<<1, 256, 0, stream>>>(bsum, boff);
    k_expand<<<NB, 256, 0, stream>>>(cnt, boff, rp);
    k_scatter<<<(E + 255) / 256, 256, 0, stream>>>(erow, ecol, eval_, cnt, ev);

    // hops
    const float* hprev = features;
    for (int i = 0; i < NUM_HOPS; ++i) {
        k_spmm<<<(N * 64 + 255) / 256, 256, 0, stream>>>(rp, ev, hprev, tmp);
        k_gemm_relu<<<(N + GR - 1) / GR, 256, 0, stream>>>(tmp, Wg + (size_t)i * NHID * NHID,
                                                           hb + (size_t)i * NF);
        hprev = hb + (size_t)i * NF;
    }

    // fused attention + fc + log_softmax
    k_attn_final<<<(N + 3) / 4, 256, 0, stream>>>(features, hb, att_w, att_b, fc_w, fc_b, out);
}

// Round 9
// 567.134 us; speedup vs baseline: 1.1347x; 1.0114x over previous
//
#include <hip/hip_runtime.h>
#include <cmath>

#define N      50000
#define E      800000
#define NFEAT  128
#define NHID   128
#define NCLASS 40
#define NUM_HOPS 4
#define NF     (N * NHID)   // 6,400,000 floats per h buffer
#define GR     64           // GEMM rows per block
#define NB     ((N + 255) / 256)   // 196 scan blocks
#define EVCAP  (E + 3 * N)  // padded edge-array capacity (pad to multiple of 4: +<=3/row)
#define XSTR   132          // LDS row stride in attn kernel (conflict break)

// ---------------- CSR build (rows padded to multiple of 4 edges) ----------------

__global__ void k_hist(const int* __restrict__ row, int* __restrict__ cnt) {
    int e = blockIdx.x * blockDim.x + threadIdx.x;
    if (e < E) atomicAdd(&cnt[row[e]], 1);
}

__global__ void k_bsum(const int* __restrict__ cnt, int* __restrict__ bsum) {
    int t = threadIdx.x;
    int i = blockIdx.x * 256 + t;
    int v = (i < N) ? ((cnt[i] + 3) & ~3) : 0;
    for (int off = 32; off; off >>= 1) v += __shfl_xor(v, off);
    __shared__ int ws[4];
    if ((t & 63) == 0) ws[t >> 6] = v;
    __syncthreads();
    if (t == 0) bsum[blockIdx.x] = ws[0] + ws[1] + ws[2] + ws[3];
}

__global__ void k_scanb(const int* __restrict__ bsum, int* __restrict__ boff) {
    __shared__ int ws[4];
    int t = threadIdx.x;
    int v = (t < NB) ? bsum[t] : 0;
    int lane = t & 63, w = t >> 6;
    int incl = v;
    for (int off = 1; off < 64; off <<= 1) {
        int u = __shfl_up(incl, off);
        if (lane >= off) incl += u;
    }
    if (lane == 63) ws[w] = incl;
    __syncthreads();
    int woff = 0;
    for (int k = 0; k < w; ++k) woff += ws[k];
    if (t < NB) boff[t] = incl - v + woff;
}

__global__ void k_expand(int* __restrict__ cnt, const int* __restrict__ boff,
                         int* __restrict__ rp) {
    __shared__ int ws[4];
    int t = threadIdx.x;
    int i = blockIdx.x * 256 + t;
    int pc = (i < N) ? ((cnt[i] + 3) & ~3) : 0;
    int lane = t & 63, w = t >> 6;
    int incl = pc;
    for (int off = 1; off < 64; off <<= 1) {
        int u = __shfl_up(incl, off);
        if (lane >= off) incl += u;
    }
    if (lane == 63) ws[w] = incl;
    __syncthreads();
    int woff = 0;
    for (int k = 0; k < w; ++k) woff += ws[k];
    int r = boff[blockIdx.x] + incl - pc + woff;
    if (i < N) {
        rp[i]  = r;
        cnt[i] = r;
        if (i == N - 1) rp[N] = r + pc;
    }
}

__global__ void k_scatter(const int* __restrict__ row, const int* __restrict__ col,
                          const float* __restrict__ val,
                          int* __restrict__ cur, int2* __restrict__ ev) {
    int e = blockIdx.x * blockDim.x + threadIdx.x;
    if (e < E) {
        int r = row[e];
        int p = atomicAdd(&cur[r], 1);
        ev[p] = make_int2(col[e], __float_as_int(val[e]));
    }
}

// ---------------- SpMM: 2 rows per wave, float4 gathers ----------------
// Each 32-lane half owns one row (16 B/lane x 32 = one 512 B x-row per gather).
// Rows padded to multiple of 4 with (col=0,val=0): exact, remainder after the
// unroll-8 main loop is exactly 0 or 4. Edge order sequential -> bit-identical h.

__global__ void k_spmm(const int* __restrict__ rp, const int2* __restrict__ ev,
                       const float* __restrict__ x, float* __restrict__ y) {
    int wid  = (blockIdx.x * blockDim.x + threadIdx.x) >> 6;   // wave id
    if (wid >= N / 2) return;
    int lane = threadIdx.x & 63;
    int half = lane >> 5;
    int sl   = lane & 31;
    int row  = wid * 2 + half;
    int beg = rp[row], end = rp[row + 1];      // uniform per half; length % 4 == 0
    float4 a = make_float4(0.f, 0.f, 0.f, 0.f);
    int j = beg;
    for (; j + 8 <= end; j += 8) {
        int2 e0 = ev[j],     e1 = ev[j + 1], e2 = ev[j + 2], e3 = ev[j + 3];
        int2 e4 = ev[j + 4], e5 = ev[j + 5], e6 = ev[j + 6], e7 = ev[j + 7];
        float4 x0 = ((const float4*)(x + (size_t)e0.x * NHID))[sl];
        float4 x1 = ((const float4*)(x + (size_t)e1.x * NHID))[sl];
        float4 x2 = ((const float4*)(x + (size_t)e2.x * NHID))[sl];
        float4 x3 = ((const float4*)(x + (size_t)e3.x * NHID))[sl];
        float4 x4 = ((const float4*)(x + (size_t)e4.x * NHID))[sl];
        float4 x5 = ((const float4*)(x + (size_t)e5.x * NHID))[sl];
        float4 x6 = ((const float4*)(x + (size_t)e6.x * NHID))[sl];
        float4 x7 = ((const float4*)(x + (size_t)e7.x * NHID))[sl];
        float v0 = __int_as_float(e0.y), v1 = __int_as_float(e1.y);
        float v2 = __int_as_float(e2.y), v3 = __int_as_float(e3.y);
        float v4 = __int_as_float(e4.y), v5 = __int_as_float(e5.y);
        float v6 = __int_as_float(e6.y), v7 = __int_as_float(e7.y);
        a.x = fmaf(v0, x0.x, a.x); a.y = fmaf(v0, x0.y, a.y); a.z = fmaf(v0, x0.z, a.z); a.w = fmaf(v0, x0.w, a.w);
        a.x = fmaf(v1, x1.x, a.x); a.y = fmaf(v1, x1.y, a.y); a.z = fmaf(v1, x1.z, a.z); a.w = fmaf(v1, x1.w, a.w);
        a.x = fmaf(v2, x2.x, a.x); a.y = fmaf(v2, x2.y, a.y); a.z = fmaf(v2, x2.z, a.z); a.w = fmaf(v2, x2.w, a.w);
        a.x = fmaf(v3, x3.x, a.x); a.y = fmaf(v3, x3.y, a.y); a.z = fmaf(v3, x3.z, a.z); a.w = fmaf(v3, x3.w, a.w);
        a.x = fmaf(v4, x4.x, a.x); a.y = fmaf(v4, x4.y, a.y); a.z = fmaf(v4, x4.z, a.z); a.w = fmaf(v4, x4.w, a.w);
        a.x = fmaf(v5, x5.x, a.x); a.y = fmaf(v5, x5.y, a.y); a.z = fmaf(v5, x5.z, a.z); a.w = fmaf(v5, x5.w, a.w);
        a.x = fmaf(v6, x6.x, a.x); a.y = fmaf(v6, x6.y, a.y); a.z = fmaf(v6, x6.z, a.z); a.w = fmaf(v6, x6.w, a.w);
        a.x = fmaf(v7, x7.x, a.x); a.y = fmaf(v7, x7.y, a.y); a.z = fmaf(v7, x7.z, a.z); a.w = fmaf(v7, x7.w, a.w);
    }
    if (j < end) {   // exactly 4 remain
        int2 e0 = ev[j], e1 = ev[j + 1], e2 = ev[j + 2], e3 = ev[j + 3];
        float4 x0 = ((const float4*)(x + (size_t)e0.x * NHID))[sl];
        float4 x1 = ((const float4*)(x + (size_t)e1.x * NHID))[sl];
        float4 x2 = ((const float4*)(x + (size_t)e2.x * NHID))[sl];
        float4 x3 = ((const float4*)(x + (size_t)e3.x * NHID))[sl];
        float v0 = __int_as_float(e0.y), v1 = __int_as_float(e1.y);
        float v2 = __int_as_float(e2.y), v3 = __int_as_float(e3.y);
        a.x = fmaf(v0, x0.x, a.x); a.y = fmaf(v0, x0.y, a.y); a.z = fmaf(v0, x0.z, a.z); a.w = fmaf(v0, x0.w, a.w);
        a.x = fmaf(v1, x1.x, a.x); a.y = fmaf(v1, x1.y, a.y); a.z = fmaf(v1, x1.z, a.z); a.w = fmaf(v1, x1.w, a.w);
        a.x = fmaf(v2, x2.x, a.x); a.y = fmaf(v2, x2.y, a.y); a.z = fmaf(v2, x2.z, a.z); a.w = fmaf(v2, x2.w, a.w);
        a.x = fmaf(v3, x3.x, a.x); a.y = fmaf(v3, x3.y, a.y); a.z = fmaf(v3, x3.z, a.z); a.w = fmaf(v3, x3.w, a.w);
    }
    ((float4*)(y + (size_t)row * NHID))[sl] = a;
}

// ---------------- GEMM (128x128 W) + ReLU + hop-score epilogue ----------------
// Epilogue computes S[row] = sum_c relu(h)[row][c] * w_h[c] from registers.

__global__ __launch_bounds__(256) void k_gemm_relu(const float* __restrict__ x,
                                                   const float* __restrict__ W,
                                                   const float* __restrict__ att_w,
                                                   float* __restrict__ y,
                                                   float* __restrict__ Sh) {
    __shared__ float xl[GR * NHID];
    int t = threadIdx.x;
    int rowbase = blockIdx.x * GR;
    int nrows = N - rowbase; if (nrows > GR) nrows = GR;
    {
        float4* xl4 = (float4*)xl;
        const float4* xg4 = (const float4*)(x + (size_t)rowbase * NHID);
        int maxq = nrows * (NHID / 4);
#pragma unroll
        for (int i = 0; i < (GR * NHID / 4) / 256; ++i) {
            int idx = i * 256 + t;
            if (idx < maxq) xl4[idx] = xg4[idx];
        }
    }
    __syncthreads();
    int cq = t & 31;          // col quad
    int rg = (t >> 5) << 3;   // row base (8 rows)
    float4 acc[8];
#pragma unroll
    for (int r = 0; r < 8; ++r) acc[r] = make_float4(0.f, 0.f, 0.f, 0.f);
    const float4* Wq = (const float4*)W;
    for (int k4 = 0; k4 < NHID / 4; ++k4) {
        float4 w0 = Wq[(4 * k4 + 0) * (NHID / 4) + cq];
        float4 w1 = Wq[(4 * k4 + 1) * (NHID / 4) + cq];
        float4 w2 = Wq[(4 * k4 + 2) * (NHID / 4) + cq];
        float4 w3 = Wq[(4 * k4 + 3) * (NHID / 4) + cq];
#pragma unroll
        for (int r = 0; r < 8; ++r) {
            float4 xv = *(const float4*)&xl[(rg + r) * NHID + 4 * k4];
            acc[r].x = fmaf(xv.x, w0.x, acc[r].x);
            acc[r].y = fmaf(xv.x, w0.y, acc[r].y);
            acc[r].z = fmaf(xv.x, w0.z, acc[r].z);
            acc[r].w = fmaf(xv.x, w0.w, acc[r].w);
            acc[r].x = fmaf(xv.y, w1.x, acc[r].x);
            acc[r].y = fmaf(xv.y, w1.y, acc[r].y);
            acc[r].z = fmaf(xv.y, w1.z, acc[r].z);
            acc[r].w = fmaf(xv.y, w1.w, acc[r].w);
            acc[r].x = fmaf(xv.z, w2.x, acc[r].x);
            acc[r].y = fmaf(xv.z, w2.y, acc[r].y);
            acc[r].z = fmaf(xv.z, w2.z, acc[r].z);
            acc[r].w = fmaf(xv.z, w2.w, acc[r].w);
            acc[r].x = fmaf(xv.w, w3.x, acc[r].x);
            acc[r].y = fmaf(xv.w, w3.y, acc[r].y);
            acc[r].z = fmaf(xv.w, w3.z, acc[r].z);
            acc[r].w = fmaf(xv.w, w3.w, acc[r].w);
        }
    }
#pragma unroll
    for (int r = 0; r < 8; ++r) {
        acc[r].x = fmaxf(acc[r].x, 0.f);
        acc[r].y = fmaxf(acc[r].y, 0.f);
        acc[r].z = fmaxf(acc[r].z, 0.f);
        acc[r].w = fmaxf(acc[r].w, 0.f);
        int row = rowbase + rg + r;
        if (row < N)
            *(float4*)(y + (size_t)row * NHID + (cq << 2)) = acc[r];
    }
    // ---- hop-score epilogue ----
    float4 whv = ((const float4*)att_w)[cq];
#pragma unroll
    for (int r = 0; r < 8; ++r) {
        float p = acc[r].x * whv.x;
        p = fmaf(acc[r].y, whv.y, p);
        p = fmaf(acc[r].z, whv.z, p);
        p = fmaf(acc[r].w, whv.w, p);
        p += __shfl_xor(p, 1);
        p += __shfl_xor(p, 2);
        p += __shfl_xor(p, 4);
        p += __shfl_xor(p, 8);
        p += __shfl_xor(p, 16);
        int row = rowbase + rg + r;
        if (cq == 0 && row < N) Sh[row] = p;
    }
}

// ---------------- Feature score: fs[node] = f[node] . w_f ----------------

__global__ void k_fscore(const float* __restrict__ f, const float* __restrict__ att_w,
                         float* __restrict__ fs) {
    int node = (blockIdx.x * blockDim.x + threadIdx.x) >> 6;
    if (node >= N) return;
    int lane = threadIdx.x & 63;
    const float2 wf = ((const float2*)(att_w + NHID))[lane];
    const float2 fv = ((const float2*)(f + (size_t)node * NFEAT))[lane];
    float s = fv.x * wf.x + fv.y * wf.y;
    for (int off = 32; off; off >>= 1) s += __shfl_xor(s, off);
    if (lane == 0) fs[node] = s;
}

// ---------------- Attention + output head, GEMM-structured (64 nodes/block) ----------------

__global__ __launch_bounds__(256) void k_attn_final(const float* __restrict__ hb,
                                                    const float* __restrict__ S,
                                                    const float* __restrict__ fs,
                                                    const float* __restrict__ att_b,
                                                    const float* __restrict__ fc_w,
                                                    const float* __restrict__ fc_b,
                                                    float* __restrict__ out) {
    __shared__ float xs[64 * XSTR];
    __shared__ float wv[4][64];
    int t = threadIdx.x;
    int base = blockIdx.x * 64;

    if (t < 64) {
        int node = base + t;
        if (node < N) {
            float b = att_b[0] + fs[node];
            float g0 = 1.f / (1.f + __expf(-(S[0 * N + node] + b)));
            float g1 = 1.f / (1.f + __expf(-(S[1 * N + node] + b)));
            float g2 = 1.f / (1.f + __expf(-(S[2 * N + node] + b)));
            float g3 = 1.f / (1.f + __expf(-(S[3 * N + node] + b)));
            float m = fmaxf(fmaxf(g0, g1), fmaxf(g2, g3));
            float e0 = __expf(g0 - m), e1 = __expf(g1 - m);
            float e2 = __expf(g2 - m), e3 = __expf(g3 - m);
            float inv = 1.f / (e0 + e1 + e2 + e3);
            wv[0][t] = e0 * inv; wv[1][t] = e1 * inv;
            wv[2][t] = e2 * inv; wv[3][t] = e3 * inv;
        } else {
            wv[0][t] = 0.f; wv[1][t] = 0.f; wv[2][t] = 0.f; wv[3][t] = 0.f;
        }
    }
    __syncthreads();

#pragma unroll
    for (int q = 0; q < 8; ++q) {
        int idx = q * 256 + t;
        int nl = idx >> 5;          // local node 0..63
        int d4 = idx & 31;          // float4 index within row
        int node = base + nl;
        float4 o = make_float4(0.f, 0.f, 0.f, 0.f);
        if (node < N) {
            float4 h0 = ((const float4*)(hb + 0 * (size_t)NF + (size_t)node * NHID))[d4];
            float4 h1 = ((const float4*)(hb + 1 * (size_t)NF + (size_t)node * NHID))[d4];
            float4 h2 = ((const float4*)(hb + 2 * (size_t)NF + (size_t)node * NHID))[d4];
            float4 h3 = ((const float4*)(hb + 3 * (size_t)NF + (size_t)node * NHID))[d4];
            float w0 = wv[0][nl], w1 = wv[1][nl], w2 = wv[2][nl], w3 = wv[3][nl];
            o.x = w0 * h0.x; o.x = fmaf(w1, h1.x, o.x); o.x = fmaf(w2, h2.x, o.x); o.x = fmaf(w3, h3.x, o.x);
            o.y = w0 * h0.y; o.y = fmaf(w1, h1.y, o.y); o.y = fmaf(w2, h2.y, o.y); o.y = fmaf(w3, h3.y, o.y);
            o.z = w0 * h0.z; o.z = fmaf(w1, h1.z, o.z); o.z = fmaf(w2, h2.z, o.z); o.z = fmaf(w3, h3.z, o.z);
            o.w = w0 * h0.w; o.w = fmaf(w1, h1.w, o.w); o.w = fmaf(w2, h2.w, o.w); o.w = fmaf(w3, h3.w, o.w);
        }
        *(float4*)&xs[nl * XSTR + (d4 << 2)] = o;
    }
    __syncthreads();

    int cq = t & 15;                     // col quad (active: cq<10)
    int rg = t >> 4;                     // row group: rows rg*4 .. rg*4+3
    int cb = (cq < 10) ? (cq << 2) : 36; // clamped col base: loads stay in-bounds
    float4 bias = *(const float4*)(fc_b + cb);
    float4 acc[4];
#pragma unroll
    for (int r = 0; r < 4; ++r) acc[r] = bias;
    for (int k4 = 0; k4 < NHID / 4; ++k4) {
        float4 w0 = *(const float4*)(fc_w + (size_t)(4 * k4 + 0) * NCLASS + cb);
        float4 w1 = *(const float4*)(fc_w + (size_t)(4 * k4 + 1) * NCLASS + cb);
        float4 w2 = *(const float4*)(fc_w + (size_t)(4 * k4 + 2) * NCLASS + cb);
        float4 w3 = *(const float4*)(fc_w + (size_t)(4 * k4 + 3) * NCLASS + cb);
#pragma unroll
        for (int r = 0; r < 4; ++r) {
            float4 xv = *(const float4*)&xs[(rg * 4 + r) * XSTR + (k4 << 2)];
            acc[r].x = fmaf(xv.x, w0.x, acc[r].x);
            acc[r].y = fmaf(xv.x, w0.y, acc[r].y);
            acc[r].z = fmaf(xv.x, w0.z, acc[r].z);
            acc[r].w = fmaf(xv.x, w0.w, acc[r].w);
            acc[r].x = fmaf(xv.y, w1.x, acc[r].x);
            acc[r].y = fmaf(xv.y, w1.y, acc[r].y);
            acc[r].z = fmaf(xv.y, w1.z, acc[r].z);
            acc[r].w = fmaf(xv.y, w1.w, acc[r].w);
            acc[r].x = fmaf(xv.z, w2.x, acc[r].x);
            acc[r].y = fmaf(xv.z, w2.y, acc[r].y);
            acc[r].z = fmaf(xv.z, w2.z, acc[r].z);
            acc[r].w = fmaf(xv.z, w2.w, acc[r].w);
            acc[r].x = fmaf(xv.w, w3.x, acc[r].x);
            acc[r].y = fmaf(xv.w, w3.y, acc[r].y);
            acc[r].z = fmaf(xv.w, w3.z, acc[r].z);
            acc[r].w = fmaf(xv.w, w3.w, acc[r].w);
        }
    }
#pragma unroll
    for (int r = 0; r < 4; ++r) {
        int nd = base + rg * 4 + r;
        float mloc = (cq < 10)
            ? fmaxf(fmaxf(acc[r].x, acc[r].y), fmaxf(acc[r].z, acc[r].w))
            : -INFINITY;
        float m = mloc;
        m = fmaxf(m, __shfl_xor(m, 1));
        m = fmaxf(m, __shfl_xor(m, 2));
        m = fmaxf(m, __shfl_xor(m, 4));
        m = fmaxf(m, __shfl_xor(m, 8));
        float sloc = (cq < 10)
            ? (__expf(acc[r].x - m) + __expf(acc[r].y - m) +
               __expf(acc[r].z - m) + __expf(acc[r].w - m))
            : 0.f;
        float s = sloc;
        s += __shfl_xor(s, 1);
        s += __shfl_xor(s, 2);
        s += __shfl_xor(s, 4);
        s += __shfl_xor(s, 8);
        float ls = m + logf(s);
        if (cq < 10 && nd < N) {
            float4 o;
            o.x = acc[r].x - ls;
            o.y = acc[r].y - ls;
            o.z = acc[r].z - ls;
            o.w = acc[r].w - ls;
            *(float4*)(out + (size_t)nd * NCLASS + cb) = o;
        }
    }
}

// ---------------- launch ----------------

extern "C" void kernel_launch(void* const* d_in, const int* in_sizes, int n_in,
                              void* d_out, int out_size, void* d_ws, size_t ws_size,
                              hipStream_t stream) {
    const float* features = (const float*)d_in[0];
    const int*   erow     = (const int*)d_in[1];
    const int*   ecol     = (const int*)d_in[2];
    const float* eval_    = (const float*)d_in[3];
    const float* Wg       = (const float*)d_in[4];
    const float* att_w    = (const float*)d_in[5];
    const float* att_b    = (const float*)d_in[6];
    const float* fc_w     = (const float*)d_in[7];
    const float* fc_b     = (const float*)d_in[8];
    float*       out      = (float*)d_out;

    // workspace layout (4-byte slots; ~137.6 MB -- strictly below the R6-proven 138.0 MB)
    const size_t SLOTS = 4 * (size_t)NF        // hb
                       + (size_t)NF            // tmp
                       + 2 * (size_t)EVCAP     // ev (int2)
                       + (N + 4)               // rp
                       + N                     // cnt (reused as fs)
                       + 2 * NB                // bsum, boff
                       + 4 * (size_t)N;        // S
    if (ws_size < SLOTS * 4) return;  // deliberate readable failure instead of OOB crash

    float* hb   = (float*)d_ws;                 // 4*NF    : h1..h4
    float* tmp  = hb + 4 * (size_t)NF;          // NF      : spmm result
    int2*  ev   = (int2*)(tmp + NF);            // EVCAP   : packed (col, val), padded rows
    int*   rp   = (int*)(ev + EVCAP);           // N+1 (+pad)
    int*   cnt  = rp + (N + 4);                 // N       : histogram / cursor / fs (reuse)
    int*   bsum = cnt + N;                      // NB      : block sums
    int*   boff = bsum + NB;                    // NB      : block offsets
    float* S    = (float*)(boff + NB);          // 4*N     : hop scores
    float* fs   = (float*)cnt;                  // alias   : cnt dead after k_scatter

    // CSR build (rows padded to x4 with col=0,val=0)
    hipMemsetAsync(cnt, 0, N * sizeof(int), stream);
    hipMemsetAsync(ev, 0, EVCAP * sizeof(int2), stream);
    k_hist<<<(E + 255) / 256, 256, 0, stream>>>(erow, cnt);
    k_bsum<<<NB, 256, 0, stream>>>(cnt, bsum);
    k_scanb<<<1, 256, 0, stream>>>(bsum, boff);
    k_expand<<<NB, 256, 0, stream>>>(cnt, boff, rp);
    k_scatter<<<(E + 255) / 256, 256, 0, stream>>>(erow, ecol, eval_, cnt, ev);

    // feature score (cnt reused as fs from here on)
    k_fscore<<<(N * 64 + 255) / 256, 256, 0, stream>>>(features, att_w, fs);

    // hops
    const float* hprev = features;
    for (int i = 0; i < NUM_HOPS; ++i) {
        k_spmm<<<((N / 2) * 64 + 255) / 256, 256, 0, stream>>>(rp, ev, hprev, tmp);
        k_gemm_relu<<<(N + GR - 1) / GR, 256, 0, stream>>>(tmp, Wg + (size_t)i * NHID * NHID,
                                                           att_w, hb + (size_t)i * NF, S + (size_t)i * N);
        hprev = hb + (size_t)i * NF;
    }

    // attention + fc + log_softmax
    k_attn_final<<<(N + 63) / 64, 256, 0, stream>>>(hb, S, fs, att_b, fc_w, fc_b, out);
}

// Round 12
// 565.822 us; speedup vs baseline: 1.1374x; 1.0023x over previous
//
#include <hip/hip_runtime.h>
#include <cmath>

#define N      50000
#define E      800000
#define NFEAT  128
#define NHID   128
#define NCLASS 40
#define NUM_HOPS 4
#define NF     (N * NHID)   // 6,400,000 floats per h buffer
#define GR     64           // GEMM rows per block
#define NB     ((N + 255) / 256)   // 196 scan blocks
#define EVCAP  (E + 3 * N)  // padded edge-array capacity (pad to multiple of 4: +<=3/row)
#define XSTR   132          // LDS row stride in attn kernel (conflict break)

// ---------------- CSR build (rows padded to multiple of 4 edges) ----------------

__global__ void k_hist(const int* __restrict__ row, int* __restrict__ cnt) {
    int e = blockIdx.x * blockDim.x + threadIdx.x;
    if (e < E) atomicAdd(&cnt[row[e]], 1);
}

__global__ void k_bsum(const int* __restrict__ cnt, int* __restrict__ bsum) {
    int t = threadIdx.x;
    int i = blockIdx.x * 256 + t;
    int v = (i < N) ? ((cnt[i] + 3) & ~3) : 0;
    for (int off = 32; off; off >>= 1) v += __shfl_xor(v, off);
    __shared__ int ws[4];
    if ((t & 63) == 0) ws[t >> 6] = v;
    __syncthreads();
    if (t == 0) bsum[blockIdx.x] = ws[0] + ws[1] + ws[2] + ws[3];
}

__global__ void k_scanb(const int* __restrict__ bsum, int* __restrict__ boff) {
    __shared__ int ws[4];
    int t = threadIdx.x;
    int v = (t < NB) ? bsum[t] : 0;
    int lane = t & 63, w = t >> 6;
    int incl = v;
    for (int off = 1; off < 64; off <<= 1) {
        int u = __shfl_up(incl, off);
        if (lane >= off) incl += u;
    }
    if (lane == 63) ws[w] = incl;
    __syncthreads();
    int woff = 0;
    for (int k = 0; k < w; ++k) woff += ws[k];
    if (t < NB) boff[t] = incl - v + woff;
}

__global__ void k_expand(int* __restrict__ cnt, const int* __restrict__ boff,
                         int* __restrict__ rp) {
    __shared__ int ws[4];
    int t = threadIdx.x;
    int i = blockIdx.x * 256 + t;
    int pc = (i < N) ? ((cnt[i] + 3) & ~3) : 0;
    int lane = t & 63, w = t >> 6;
    int incl = pc;
    for (int off = 1; off < 64; off <<= 1) {
        int u = __shfl_up(incl, off);
        if (lane >= off) incl += u;
    }
    if (lane == 63) ws[w] = incl;
    __syncthreads();
    int woff = 0;
    for (int k = 0; k < w; ++k) woff += ws[k];
    int r = boff[blockIdx.x] + incl - pc + woff;
    if (i < N) {
        rp[i]  = r;
        cnt[i] = r;
        if (i == N - 1) rp[N] = r + pc;
    }
}

__global__ void k_scatter(const int* __restrict__ row, const int* __restrict__ col,
                          const float* __restrict__ val,
                          int* __restrict__ cur, int2* __restrict__ ev) {
    int e = blockIdx.x * blockDim.x + threadIdx.x;
    if (e < E) {
        int r = row[e];
        int p = atomicAdd(&cur[r], 1);
        ev[p] = make_int2(col[e], __float_as_int(val[e]));
    }
}

// ---------------- SpMM: 2 rows per wave, float4 gathers ----------------
// Each 32-lane half owns one row (16 B/lane x 32 = one 512 B x-row per gather).
// Rows padded to multiple of 4 with (col=0,val=0): exact, remainder after the
// unroll-8 main loop is exactly 0 or 4. Edge order sequential -> bit-identical h.

__global__ void k_spmm(const int* __restrict__ rp, const int2* __restrict__ ev,
                       const float* __restrict__ x, float* __restrict__ y) {
    int wid  = (blockIdx.x * blockDim.x + threadIdx.x) >> 6;   // wave id
    if (wid >= N / 2) return;
    int lane = threadIdx.x & 63;
    int half = lane >> 5;
    int sl   = lane & 31;
    int row  = wid * 2 + half;
    int beg = rp[row], end = rp[row + 1];      // uniform per half; length % 4 == 0
    float4 a = make_float4(0.f, 0.f, 0.f, 0.f);
    int j = beg;
    for (; j + 8 <= end; j += 8) {
        int2 e0 = ev[j],     e1 = ev[j + 1], e2 = ev[j + 2], e3 = ev[j + 3];
        int2 e4 = ev[j + 4], e5 = ev[j + 5], e6 = ev[j + 6], e7 = ev[j + 7];
        float4 x0 = ((const float4*)(x + (size_t)e0.x * NHID))[sl];
        float4 x1 = ((const float4*)(x + (size_t)e1.x * NHID))[sl];
        float4 x2 = ((const float4*)(x + (size_t)e2.x * NHID))[sl];
        float4 x3 = ((const float4*)(x + (size_t)e3.x * NHID))[sl];
        float4 x4 = ((const float4*)(x + (size_t)e4.x * NHID))[sl];
        float4 x5 = ((const float4*)(x + (size_t)e5.x * NHID))[sl];
        float4 x6 = ((const float4*)(x + (size_t)e6.x * NHID))[sl];
        float4 x7 = ((const float4*)(x + (size_t)e7.x * NHID))[sl];
        float v0 = __int_as_float(e0.y), v1 = __int_as_float(e1.y);
        float v2 = __int_as_float(e2.y), v3 = __int_as_float(e3.y);
        float v4 = __int_as_float(e4.y), v5 = __int_as_float(e5.y);
        float v6 = __int_as_float(e6.y), v7 = __int_as_float(e7.y);
        a.x = fmaf(v0, x0.x, a.x); a.y = fmaf(v0, x0.y, a.y); a.z = fmaf(v0, x0.z, a.z); a.w = fmaf(v0, x0.w, a.w);
        a.x = fmaf(v1, x1.x, a.x); a.y = fmaf(v1, x1.y, a.y); a.z = fmaf(v1, x1.z, a.z); a.w = fmaf(v1, x1.w, a.w);
        a.x = fmaf(v2, x2.x, a.x); a.y = fmaf(v2, x2.y, a.y); a.z = fmaf(v2, x2.z, a.z); a.w = fmaf(v2, x2.w, a.w);
        a.x = fmaf(v3, x3.x, a.x); a.y = fmaf(v3, x3.y, a.y); a.z = fmaf(v3, x3.z, a.z); a.w = fmaf(v3, x3.w, a.w);
        a.x = fmaf(v4, x4.x, a.x); a.y = fmaf(v4, x4.y, a.y); a.z = fmaf(v4, x4.z, a.z); a.w = fmaf(v4, x4.w, a.w);
        a.x = fmaf(v5, x5.x, a.x); a.y = fmaf(v5, x5.y, a.y); a.z = fmaf(v5, x5.z, a.z); a.w = fmaf(v5, x5.w, a.w);
        a.x = fmaf(v6, x6.x, a.x); a.y = fmaf(v6, x6.y, a.y); a.z = fmaf(v6, x6.z, a.z); a.w = fmaf(v6, x6.w, a.w);
        a.x = fmaf(v7, x7.x, a.x); a.y = fmaf(v7, x7.y, a.y); a.z = fmaf(v7, x7.z, a.z); a.w = fmaf(v7, x7.w, a.w);
    }
    if (j < end) {   // exactly 4 remain
        int2 e0 = ev[j], e1 = ev[j + 1], e2 = ev[j + 2], e3 = ev[j + 3];
        float4 x0 = ((const float4*)(x + (size_t)e0.x * NHID))[sl];
        float4 x1 = ((const float4*)(x + (size_t)e1.x * NHID))[sl];
        float4 x2 = ((const float4*)(x + (size_t)e2.x * NHID))[sl];
        float4 x3 = ((const float4*)(x + (size_t)e3.x * NHID))[sl];
        float v0 = __int_as_float(e0.y), v1 = __int_as_float(e1.y);
        float v2 = __int_as_float(e2.y), v3 = __int_as_float(e3.y);
        a.x = fmaf(v0, x0.x, a.x); a.y = fmaf(v0, x0.y, a.y); a.z = fmaf(v0, x0.z, a.z); a.w = fmaf(v0, x0.w, a.w);
        a.x = fmaf(v1, x1.x, a.x); a.y = fmaf(v1, x1.y, a.y); a.z = fmaf(v1, x1.z, a.z); a.w = fmaf(v1, x1.w, a.w);
        a.x = fmaf(v2, x2.x, a.x); a.y = fmaf(v2, x2.y, a.y); a.z = fmaf(v2, x2.z, a.z); a.w = fmaf(v2, x2.w, a.w);
        a.x = fmaf(v3, x3.x, a.x); a.y = fmaf(v3, x3.y, a.y); a.z = fmaf(v3, x3.z, a.z); a.w = fmaf(v3, x3.w, a.w);
    }
    ((float4*)(y + (size_t)row * NHID))[sl] = a;
}

// ---------------- GEMM (128x128 W) + ReLU + hop-score epilogue ----------------
// Epilogue computes S[row] = sum_c relu(h)[row][c] * w_h[c] from registers.

__global__ __launch_bounds__(256) void k_gemm_relu(const float* __restrict__ x,
                                                   const float* __restrict__ W,
                                                   const float* __restrict__ att_w,
                                                   float* __restrict__ y,
                                                   float* __restrict__ Sh) {
    __shared__ float xl[GR * NHID];
    int t = threadIdx.x;
    int rowbase = blockIdx.x * GR;
    int nrows = N - rowbase; if (nrows > GR) nrows = GR;
    {
        float4* xl4 = (float4*)xl;
        const float4* xg4 = (const float4*)(x + (size_t)rowbase * NHID);
        int maxq = nrows * (NHID / 4);
#pragma unroll
        for (int i = 0; i < (GR * NHID / 4) / 256; ++i) {
            int idx = i * 256 + t;
            if (idx < maxq) xl4[idx] = xg4[idx];
        }
    }
    __syncthreads();
    int cq = t & 31;          // col quad
    int rg = (t >> 5) << 3;   // row base (8 rows)
    float4 acc[8];
#pragma unroll
    for (int r = 0; r < 8; ++r) acc[r] = make_float4(0.f, 0.f, 0.f, 0.f);
    const float4* Wq = (const float4*)W;
    for (int k4 = 0; k4 < NHID / 4; ++k4) {
        float4 w0 = Wq[(4 * k4 + 0) * (NHID / 4) + cq];
        float4 w1 = Wq[(4 * k4 + 1) * (NHID / 4) + cq];
        float4 w2 = Wq[(4 * k4 + 2) * (NHID / 4) + cq];
        float4 w3 = Wq[(4 * k4 + 3) * (NHID / 4) + cq];
#pragma unroll
        for (int r = 0; r < 8; ++r) {
            float4 xv = *(const float4*)&xl[(rg + r) * NHID + 4 * k4];
            acc[r].x = fmaf(xv.x, w0.x, acc[r].x);
            acc[r].y = fmaf(xv.x, w0.y, acc[r].y);
            acc[r].z = fmaf(xv.x, w0.z, acc[r].z);
            acc[r].w = fmaf(xv.x, w0.w, acc[r].w);
            acc[r].x = fmaf(xv.y, w1.x, acc[r].x);
            acc[r].y = fmaf(xv.y, w1.y, acc[r].y);
            acc[r].z = fmaf(xv.y, w1.z, acc[r].z);
            acc[r].w = fmaf(xv.y, w1.w, acc[r].w);
            acc[r].x = fmaf(xv.z, w2.x, acc[r].x);
            acc[r].y = fmaf(xv.z, w2.y, acc[r].y);
            acc[r].z = fmaf(xv.z, w2.z, acc[r].z);
            acc[r].w = fmaf(xv.z, w2.w, acc[r].w);
            acc[r].x = fmaf(xv.w, w3.x, acc[r].x);
            acc[r].y = fmaf(xv.w, w3.y, acc[r].y);
            acc[r].z = fmaf(xv.w, w3.z, acc[r].z);
            acc[r].w = fmaf(xv.w, w3.w, acc[r].w);
        }
    }
#pragma unroll
    for (int r = 0; r < 8; ++r) {
        acc[r].x = fmaxf(acc[r].x, 0.f);
        acc[r].y = fmaxf(acc[r].y, 0.f);
        acc[r].z = fmaxf(acc[r].z, 0.f);
        acc[r].w = fmaxf(acc[r].w, 0.f);
        int row = rowbase + rg + r;
        if (row < N)
            *(float4*)(y + (size_t)row * NHID + (cq << 2)) = acc[r];
    }
    // ---- hop-score epilogue ----
    float4 whv = ((const float4*)att_w)[cq];
#pragma unroll
    for (int r = 0; r < 8; ++r) {
        float p = acc[r].x * whv.x;
        p = fmaf(acc[r].y, whv.y, p);
        p = fmaf(acc[r].z, whv.z, p);
        p = fmaf(acc[r].w, whv.w, p);
        p += __shfl_xor(p, 1);
        p += __shfl_xor(p, 2);
        p += __shfl_xor(p, 4);
        p += __shfl_xor(p, 8);
        p += __shfl_xor(p, 16);
        int row = rowbase + rg + r;
        if (cq == 0 && row < N) Sh[row] = p;
    }
}

// ---------------- Feature score: fs[node] = f[node] . w_f ----------------

__global__ void k_fscore(const float* __restrict__ f, const float* __restrict__ att_w,
                         float* __restrict__ fs) {
    int node = (blockIdx.x * blockDim.x + threadIdx.x) >> 6;
    if (node >= N) return;
    int lane = threadIdx.x & 63;
    const float2 wf = ((const float2*)(att_w + NHID))[lane];
    const float2 fv = ((const float2*)(f + (size_t)node * NFEAT))[lane];
    float s = fv.x * wf.x + fv.y * wf.y;
    for (int off = 32; off; off >>= 1) s += __shfl_xor(s, off);
    if (lane == 0) fs[node] = s;
}

// ---------------- Attention + output head, GEMM-structured (64 nodes/block) ----------------

__global__ __launch_bounds__(256) void k_attn_final(const float* __restrict__ hb,
                                                    const float* __restrict__ S,
                                                    const float* __restrict__ fs,
                                                    const float* __restrict__ att_b,
                                                    const float* __restrict__ fc_w,
                                                    const float* __restrict__ fc_b,
                                                    float* __restrict__ out) {
    __shared__ float xs[64 * XSTR];
    __shared__ float wv[4][64];
    int t = threadIdx.x;
    int base = blockIdx.x * 64;

    if (t < 64) {
        int node = base + t;
        if (node < N) {
            float b = att_b[0] + fs[node];
            float g0 = 1.f / (1.f + __expf(-(S[0 * N + node] + b)));
            float g1 = 1.f / (1.f + __expf(-(S[1 * N + node] + b)));
            float g2 = 1.f / (1.f + __expf(-(S[2 * N + node] + b)));
            float g3 = 1.f / (1.f + __expf(-(S[3 * N + node] + b)));
            float m = fmaxf(fmaxf(g0, g1), fmaxf(g2, g3));
            float e0 = __expf(g0 - m), e1 = __expf(g1 - m);
            float e2 = __expf(g2 - m), e3 = __expf(g3 - m);
            float inv = 1.f / (e0 + e1 + e2 + e3);
            wv[0][t] = e0 * inv; wv[1][t] = e1 * inv;
            wv[2][t] = e2 * inv; wv[3][t] = e3 * inv;
        } else {
            wv[0][t] = 0.f; wv[1][t] = 0.f; wv[2][t] = 0.f; wv[3][t] = 0.f;
        }
    }
    __syncthreads();

#pragma unroll
    for (int q = 0; q < 8; ++q) {
        int idx = q * 256 + t;
        int nl = idx >> 5;          // local node 0..63
        int d4 = idx & 31;          // float4 index within row
        int node = base + nl;
        float4 o = make_float4(0.f, 0.f, 0.f, 0.f);
        if (node < N) {
            float4 h0 = ((const float4*)(hb + 0 * (size_t)NF + (size_t)node * NHID))[d4];
            float4 h1 = ((const float4*)(hb + 1 * (size_t)NF + (size_t)node * NHID))[d4];
            float4 h2 = ((const float4*)(hb + 2 * (size_t)NF + (size_t)node * NHID))[d4];
            float4 h3 = ((const float4*)(hb + 3 * (size_t)NF + (size_t)node * NHID))[d4];
            float w0 = wv[0][nl], w1 = wv[1][nl], w2 = wv[2][nl], w3 = wv[3][nl];
            o.x = w0 * h0.x; o.x = fmaf(w1, h1.x, o.x); o.x = fmaf(w2, h2.x, o.x); o.x = fmaf(w3, h3.x, o.x);
            o.y = w0 * h0.y; o.y = fmaf(w1, h1.y, o.y); o.y = fmaf(w2, h2.y, o.y); o.y = fmaf(w3, h3.y, o.y);
            o.z = w0 * h0.z; o.z = fmaf(w1, h1.z, o.z); o.z = fmaf(w2, h2.z, o.z); o.z = fmaf(w3, h3.z, o.z);
            o.w = w0 * h0.w; o.w = fmaf(w1, h1.w, o.w); o.w = fmaf(w2, h2.w, o.w); o.w = fmaf(w3, h3.w, o.w);
        }
        *(float4*)&xs[nl * XSTR + (d4 << 2)] = o;
    }
    __syncthreads();

    int cq = t & 15;                     // col quad (active: cq<10)
    int rg = t >> 4;                     // row group: rows rg*4 .. rg*4+3
    int cb = (cq < 10) ? (cq << 2) : 36; // clamped col base: loads stay in-bounds
    float4 bias = *(const float4*)(fc_b + cb);
    float4 acc[4];
#pragma unroll
    for (int r = 0; r < 4; ++r) acc[r] = bias;
    for (int k4 = 0; k4 < NHID / 4; ++k4) {
        float4 w0 = *(const float4*)(fc_w + (size_t)(4 * k4 + 0) * NCLASS + cb);
        float4 w1 = *(const float4*)(fc_w + (size_t)(4 * k4 + 1) * NCLASS + cb);
        float4 w2 = *(const float4*)(fc_w + (size_t)(4 * k4 + 2) * NCLASS + cb);
        float4 w3 = *(const float4*)(fc_w + (size_t)(4 * k4 + 3) * NCLASS + cb);
#pragma unroll
        for (int r = 0; r < 4; ++r) {
            float4 xv = *(const float4*)&xs[(rg * 4 + r) * XSTR + (k4 << 2)];
            acc[r].x = fmaf(xv.x, w0.x, acc[r].x);
            acc[r].y = fmaf(xv.x, w0.y, acc[r].y);
            acc[r].z = fmaf(xv.x, w0.z, acc[r].z);
            acc[r].w = fmaf(xv.x, w0.w, acc[r].w);
            acc[r].x = fmaf(xv.y, w1.x, acc[r].x);
            acc[r].y = fmaf(xv.y, w1.y, acc[r].y);
            acc[r].z = fmaf(xv.y, w1.z, acc[r].z);
            acc[r].w = fmaf(xv.y, w1.w, acc[r].w);
            acc[r].x = fmaf(xv.z, w2.x, acc[r].x);
            acc[r].y = fmaf(xv.z, w2.y, acc[r].y);
            acc[r].z = fmaf(xv.z, w2.z, acc[r].z);
            acc[r].w = fmaf(xv.z, w2.w, acc[r].w);
            acc[r].x = fmaf(xv.w, w3.x, acc[r].x);
            acc[r].y = fmaf(xv.w, w3.y, acc[r].y);
            acc[r].z = fmaf(xv.w, w3.z, acc[r].z);
            acc[r].w = fmaf(xv.w, w3.w, acc[r].w);
        }
    }
#pragma unroll
    for (int r = 0; r < 4; ++r) {
        int nd = base + rg * 4 + r;
        float mloc = (cq < 10)
            ? fmaxf(fmaxf(acc[r].x, acc[r].y), fmaxf(acc[r].z, acc[r].w))
            : -INFINITY;
        float m = mloc;
        m = fmaxf(m, __shfl_xor(m, 1));
        m = fmaxf(m, __shfl_xor(m, 2));
        m = fmaxf(m, __shfl_xor(m, 4));
        m = fmaxf(m, __shfl_xor(m, 8));
        float sloc = (cq < 10)
            ? (__expf(acc[r].x - m) + __expf(acc[r].y - m) +
               __expf(acc[r].z - m) + __expf(acc[r].w - m))
            : 0.f;
        float s = sloc;
        s += __shfl_xor(s, 1);
        s += __shfl_xor(s, 2);
        s += __shfl_xor(s, 4);
        s += __shfl_xor(s, 8);
        float ls = m + logf(s);
        if (cq < 10 && nd < N) {
            float4 o;
            o.x = acc[r].x - ls;
            o.y = acc[r].y - ls;
            o.z = acc[r].z - ls;
            o.w = acc[r].w - ls;
            *(float4*)(out + (size_t)nd * NCLASS + cb) = o;
        }
    }
}

// ---------------- launch ----------------

extern "C" void kernel_launch(void* const* d_in, const int* in_sizes, int n_in,
                              void* d_out, int out_size, void* d_ws, size_t ws_size,
                              hipStream_t stream) {
    const float* features = (const float*)d_in[0];
    const int*   erow     = (const int*)d_in[1];
    const int*   ecol     = (const int*)d_in[2];
    const float* eval_    = (const float*)d_in[3];
    const float* Wg       = (const float*)d_in[4];
    const float* att_w    = (const float*)d_in[5];
    const float* att_b    = (const float*)d_in[6];
    const float* fc_w     = (const float*)d_in[7];
    const float* fc_b     = (const float*)d_in[8];
    float*       out      = (float*)d_out;

    // workspace layout (4-byte slots; ~137.6 MB -- strictly below the R6-proven 138.0 MB)
    const size_t SLOTS = 4 * (size_t)NF        // hb
                       + (size_t)NF            // tmp
                       + 2 * (size_t)EVCAP     // ev (int2)
                       + (N + 4)               // rp
                       + N                     // cnt (reused as fs)
                       + 2 * NB                // bsum, boff
                       + 4 * (size_t)N;        // S
    if (ws_size < SLOTS * 4) return;  // deliberate readable failure instead of OOB crash

    float* hb   = (float*)d_ws;                 // 4*NF    : h1..h4
    float* tmp  = hb + 4 * (size_t)NF;          // NF      : spmm result
    int2*  ev   = (int2*)(tmp + NF);            // EVCAP   : packed (col, val), padded rows
    int*   rp   = (int*)(ev + EVCAP);           // N+1 (+pad)
    int*   cnt  = rp + (N + 4);                 // N       : histogram / cursor / fs (reuse)
    int*   bsum = cnt + N;                      // NB      : block sums
    int*   boff = bsum + NB;                    // NB      : block offsets
    float* S    = (float*)(boff + NB);          // 4*N     : hop scores
    float* fs   = (float*)cnt;                  // alias   : cnt dead after k_scatter

    // CSR build (rows padded to x4 with col=0,val=0)
    hipMemsetAsync(cnt, 0, N * sizeof(int), stream);
    hipMemsetAsync(ev, 0, EVCAP * sizeof(int2), stream);
    k_hist<<<(E + 255) / 256, 256, 0, stream>>>(erow, cnt);
    k_bsum<<<NB, 256, 0, stream>>>(cnt, bsum);
    k_scanb<<<1, 256, 0, stream>>>(bsum, boff);
    k_expand<<<NB, 256, 0, stream>>>(cnt, boff, rp);
    k_scatter<<<(E + 255) / 256, 256, 0, stream>>>(erow, ecol, eval_, cnt, ev);

    // feature score (cnt reused as fs from here on)
    k_fscore<<<(N * 64 + 255) / 256, 256, 0, stream>>>(features, att_w, fs);

    // hops
    const float* hprev = features;
    for (int i = 0; i < NUM_HOPS; ++i) {
        k_spmm<<<((N / 2) * 64 + 255) / 256, 256, 0, stream>>>(rp, ev, hprev, tmp);
        k_gemm_relu<<<(N + GR - 1) / GR, 256, 0, stream>>>(tmp, Wg + (size_t)i * NHID * NHID,
                                                           att_w, hb + (size_t)i * NF, S + (size_t)i * N);
        hprev = hb + (size_t)i * NF;
    }

    // attention + fc + log_softmax
    k_attn_final<<<(N + 63) / 64, 256, 0, stream>>>(hb, S, fs, att_b, fc_w, fc_b, out);
}

// Round 13
// 466.027 us; speedup vs baseline: 1.3809x; 1.2141x over previous
//
#include <hip/hip_runtime.h>
#include <cmath>

#define N      50000
#define E      800000
#define NFEAT  128
#define NHID   128
#define NCLASS 40
#define NUM_HOPS 4
#define NF     (N * NHID)   // 6,400,000 elements per h buffer
#define GR     64           // GEMM rows per block
#define NB     ((N + 255) / 256)   // 196 scan blocks
#define EVCAP  (E + 3 * N)  // padded edge-array capacity (pad to multiple of 4)
#define XSTR   132          // LDS row stride in attn kernel (conflict break)

// bf16 helpers: RTNE pack of two floats into one dword; unpack by shift.
__device__ __forceinline__ unsigned bf16pack(float a, float b) {
    unsigned ua = __float_as_uint(a), ub = __float_as_uint(b);
    ua = (ua + 0x7fffu + ((ua >> 16) & 1u)) >> 16;
    ub = (ub + 0x7fffu + ((ub >> 16) & 1u)) >> 16;
    return ua | (ub << 16);
}
__device__ __forceinline__ float bf16lo(unsigned u) { return __uint_as_float(u << 16); }
__device__ __forceinline__ float bf16hi(unsigned u) { return __uint_as_float(u & 0xffff0000u); }

// ---------------- CSR build (rows padded to multiple of 4 edges) ----------------

__global__ void k_hist(const int* __restrict__ row, int* __restrict__ cnt) {
    int e = blockIdx.x * blockDim.x + threadIdx.x;
    if (e < E) atomicAdd(&cnt[row[e]], 1);
}

__global__ void k_bsum(const int* __restrict__ cnt, int* __restrict__ bsum) {
    int t = threadIdx.x;
    int i = blockIdx.x * 256 + t;
    int v = (i < N) ? ((cnt[i] + 3) & ~3) : 0;
    for (int off = 32; off; off >>= 1) v += __shfl_xor(v, off);
    __shared__ int ws[4];
    if ((t & 63) == 0) ws[t >> 6] = v;
    __syncthreads();
    if (t == 0) bsum[blockIdx.x] = ws[0] + ws[1] + ws[2] + ws[3];
}

__global__ void k_scanb(const int* __restrict__ bsum, int* __restrict__ boff) {
    __shared__ int ws[4];
    int t = threadIdx.x;
    int v = (t < NB) ? bsum[t] : 0;
    int lane = t & 63, w = t >> 6;
    int incl = v;
    for (int off = 1; off < 64; off <<= 1) {
        int u = __shfl_up(incl, off);
        if (lane >= off) incl += u;
    }
    if (lane == 63) ws[w] = incl;
    __syncthreads();
    int woff = 0;
    for (int k = 0; k < w; ++k) woff += ws[k];
    if (t < NB) boff[t] = incl - v + woff;
}

__global__ void k_expand(int* __restrict__ cnt, const int* __restrict__ boff,
                         int* __restrict__ rp) {
    __shared__ int ws[4];
    int t = threadIdx.x;
    int i = blockIdx.x * 256 + t;
    int pc = (i < N) ? ((cnt[i] + 3) & ~3) : 0;
    int lane = t & 63, w = t >> 6;
    int incl = pc;
    for (int off = 1; off < 64; off <<= 1) {
        int u = __shfl_up(incl, off);
        if (lane >= off) incl += u;
    }
    if (lane == 63) ws[w] = incl;
    __syncthreads();
    int woff = 0;
    for (int k = 0; k < w; ++k) woff += ws[k];
    int r = boff[blockIdx.x] + incl - pc + woff;
    if (i < N) {
        rp[i]  = r;
        cnt[i] = r;
        if (i == N - 1) rp[N] = r + pc;
    }
}

__global__ void k_scatter(const int* __restrict__ row, const int* __restrict__ col,
                          const float* __restrict__ val,
                          int* __restrict__ cur, int2* __restrict__ ev) {
    int e = blockIdx.x * blockDim.x + threadIdx.x;
    if (e < E) {
        int r = row[e];
        int p = atomicAdd(&cur[r], 1);
        ev[p] = make_int2(col[e], __float_as_int(val[e]));
    }
}

// ---------------- f32 -> bf16 convert (features) ----------------

__global__ void k_cvt(const float* __restrict__ f, unsigned short* __restrict__ fb) {
    int i = blockIdx.x * blockDim.x + threadIdx.x;   // one float4 per thread
    if (i >= NF / 4) return;
    float4 v = ((const float4*)f)[i];
    uint2 o;
    o.x = bf16pack(v.x, v.y);
    o.y = bf16pack(v.z, v.w);
    ((uint2*)fb)[i] = o;
}

// ---------------- SpMM: 4 rows per wave, bf16 x, f32 accumulate ----------------
// Each 16-lane quarter owns one row (256 B bf16 = 16 lanes x 16 B -> one row per
// gather instruction). Unroll-8 -> 8 KB in flight per wave. Rows padded to
// multiple of 4 (col=0,val=0: exact). Edge order sequential per element ->
// same accumulation order as R9/R12, x rounded to bf16 (RTNE).

__global__ void k_spmm(const int* __restrict__ rp, const int2* __restrict__ ev,
                       const unsigned short* __restrict__ xb, float* __restrict__ y) {
    int wid  = (blockIdx.x * blockDim.x + threadIdx.x) >> 6;   // wave id
    if (wid >= N / 4) return;
    int lane = threadIdx.x & 63;
    int q  = lane >> 4;       // quarter 0..3
    int ql = lane & 15;       // lane within quarter
    int row = wid * 4 + q;
    int beg = rp[row], end = rp[row + 1];      // uniform per quarter; length % 4 == 0
    float a0 = 0.f, a1 = 0.f, a2 = 0.f, a3 = 0.f;
    float a4 = 0.f, a5 = 0.f, a6 = 0.f, a7 = 0.f;
    const uint4* xq = (const uint4*)xb;        // row r -> base index r*16
#define ACC8(g, v)                                                        \
    do {                                                                  \
        a0 = fmaf((v), bf16lo((g).x), a0); a1 = fmaf((v), bf16hi((g).x), a1); \
        a2 = fmaf((v), bf16lo((g).y), a2); a3 = fmaf((v), bf16hi((g).y), a3); \
        a4 = fmaf((v), bf16lo((g).z), a4); a5 = fmaf((v), bf16hi((g).z), a5); \
        a6 = fmaf((v), bf16lo((g).w), a6); a7 = fmaf((v), bf16hi((g).w), a7); \
    } while (0)
    int j = beg;
    for (; j + 8 <= end; j += 8) {
        int2 e0 = ev[j],     e1 = ev[j + 1], e2 = ev[j + 2], e3 = ev[j + 3];
        int2 e4 = ev[j + 4], e5 = ev[j + 5], e6 = ev[j + 6], e7 = ev[j + 7];
        uint4 g0 = xq[(size_t)e0.x * 16 + ql];
        uint4 g1 = xq[(size_t)e1.x * 16 + ql];
        uint4 g2 = xq[(size_t)e2.x * 16 + ql];
        uint4 g3 = xq[(size_t)e3.x * 16 + ql];
        uint4 g4 = xq[(size_t)e4.x * 16 + ql];
        uint4 g5 = xq[(size_t)e5.x * 16 + ql];
        uint4 g6 = xq[(size_t)e6.x * 16 + ql];
        uint4 g7 = xq[(size_t)e7.x * 16 + ql];
        ACC8(g0, __int_as_float(e0.y));
        ACC8(g1, __int_as_float(e1.y));
        ACC8(g2, __int_as_float(e2.y));
        ACC8(g3, __int_as_float(e3.y));
        ACC8(g4, __int_as_float(e4.y));
        ACC8(g5, __int_as_float(e5.y));
        ACC8(g6, __int_as_float(e6.y));
        ACC8(g7, __int_as_float(e7.y));
    }
    if (j < end) {   // exactly 4 remain
        int2 e0 = ev[j], e1 = ev[j + 1], e2 = ev[j + 2], e3 = ev[j + 3];
        uint4 g0 = xq[(size_t)e0.x * 16 + ql];
        uint4 g1 = xq[(size_t)e1.x * 16 + ql];
        uint4 g2 = xq[(size_t)e2.x * 16 + ql];
        uint4 g3 = xq[(size_t)e3.x * 16 + ql];
        ACC8(g0, __int_as_float(e0.y));
        ACC8(g1, __int_as_float(e1.y));
        ACC8(g2, __int_as_float(e2.y));
        ACC8(g3, __int_as_float(e3.y));
    }
#undef ACC8
    float* yr = y + (size_t)row * NHID + ql * 8;
    *(float4*)yr       = make_float4(a0, a1, a2, a3);
    *(float4*)(yr + 4) = make_float4(a4, a5, a6, a7);
}

// ---------------- GEMM (128x128 W) + ReLU + bf16 store + hop-score epilogue ----------------
// Scores computed from pre-rounding f32 registers (closer to reference).

__global__ __launch_bounds__(256) void k_gemm_relu(const float* __restrict__ x,
                                                   const float* __restrict__ W,
                                                   const float* __restrict__ att_w,
                                                   unsigned short* __restrict__ yb,
                                                   float* __restrict__ Sh) {
    __shared__ float xl[GR * NHID];
    int t = threadIdx.x;
    int rowbase = blockIdx.x * GR;
    int nrows = N - rowbase; if (nrows > GR) nrows = GR;
    {
        float4* xl4 = (float4*)xl;
        const float4* xg4 = (const float4*)(x + (size_t)rowbase * NHID);
        int maxq = nrows * (NHID / 4);
#pragma unroll
        for (int i = 0; i < (GR * NHID / 4) / 256; ++i) {
            int idx = i * 256 + t;
            if (idx < maxq) xl4[idx] = xg4[idx];
        }
    }
    __syncthreads();
    int cq = t & 31;          // col quad
    int rg = (t >> 5) << 3;   // row base (8 rows)
    float4 acc[8];
#pragma unroll
    for (int r = 0; r < 8; ++r) acc[r] = make_float4(0.f, 0.f, 0.f, 0.f);
    const float4* Wq = (const float4*)W;
    for (int k4 = 0; k4 < NHID / 4; ++k4) {
        float4 w0 = Wq[(4 * k4 + 0) * (NHID / 4) + cq];
        float4 w1 = Wq[(4 * k4 + 1) * (NHID / 4) + cq];
        float4 w2 = Wq[(4 * k4 + 2) * (NHID / 4) + cq];
        float4 w3 = Wq[(4 * k4 + 3) * (NHID / 4) + cq];
#pragma unroll
        for (int r = 0; r < 8; ++r) {
            float4 xv = *(const float4*)&xl[(rg + r) * NHID + 4 * k4];
            acc[r].x = fmaf(xv.x, w0.x, acc[r].x);
            acc[r].y = fmaf(xv.x, w0.y, acc[r].y);
            acc[r].z = fmaf(xv.x, w0.z, acc[r].z);
            acc[r].w = fmaf(xv.x, w0.w, acc[r].w);
            acc[r].x = fmaf(xv.y, w1.x, acc[r].x);
            acc[r].y = fmaf(xv.y, w1.y, acc[r].y);
            acc[r].z = fmaf(xv.y, w1.z, acc[r].z);
            acc[r].w = fmaf(xv.y, w1.w, acc[r].w);
            acc[r].x = fmaf(xv.z, w2.x, acc[r].x);
            acc[r].y = fmaf(xv.z, w2.y, acc[r].y);
            acc[r].z = fmaf(xv.z, w2.z, acc[r].z);
            acc[r].w = fmaf(xv.z, w2.w, acc[r].w);
            acc[r].x = fmaf(xv.w, w3.x, acc[r].x);
            acc[r].y = fmaf(xv.w, w3.y, acc[r].y);
            acc[r].z = fmaf(xv.w, w3.z, acc[r].z);
            acc[r].w = fmaf(xv.w, w3.w, acc[r].w);
        }
    }
#pragma unroll
    for (int r = 0; r < 8; ++r) {
        acc[r].x = fmaxf(acc[r].x, 0.f);
        acc[r].y = fmaxf(acc[r].y, 0.f);
        acc[r].z = fmaxf(acc[r].z, 0.f);
        acc[r].w = fmaxf(acc[r].w, 0.f);
        int row = rowbase + rg + r;
        if (row < N) {
            uint2 o;
            o.x = bf16pack(acc[r].x, acc[r].y);
            o.y = bf16pack(acc[r].z, acc[r].w);
            *(uint2*)(yb + (size_t)row * NHID + (cq << 2)) = o;
        }
    }
    // ---- hop-score epilogue (pre-rounding f32 values) ----
    float4 whv = ((const float4*)att_w)[cq];
#pragma unroll
    for (int r = 0; r < 8; ++r) {
        float p = acc[r].x * whv.x;
        p = fmaf(acc[r].y, whv.y, p);
        p = fmaf(acc[r].z, whv.z, p);
        p = fmaf(acc[r].w, whv.w, p);
        p += __shfl_xor(p, 1);
        p += __shfl_xor(p, 2);
        p += __shfl_xor(p, 4);
        p += __shfl_xor(p, 8);
        p += __shfl_xor(p, 16);
        int row = rowbase + rg + r;
        if (cq == 0 && row < N) Sh[row] = p;
    }
}

// ---------------- Feature score: fs[node] = f[node] . w_f (f32 features) ----------------

__global__ void k_fscore(const float* __restrict__ f, const float* __restrict__ att_w,
                         float* __restrict__ fs) {
    int node = (blockIdx.x * blockDim.x + threadIdx.x) >> 6;
    if (node >= N) return;
    int lane = threadIdx.x & 63;
    const float2 wf = ((const float2*)(att_w + NHID))[lane];
    const float2 fv = ((const float2*)(f + (size_t)node * NFEAT))[lane];
    float s = fv.x * wf.x + fv.y * wf.y;
    for (int off = 32; off; off >>= 1) s += __shfl_xor(s, off);
    if (lane == 0) fs[node] = s;
}

// ---------------- Attention + output head (64 nodes/block, bf16 h input) ----------------

__global__ __launch_bounds__(256) void k_attn_final(const unsigned short* __restrict__ hb,
                                                    const float* __restrict__ S,
                                                    const float* __restrict__ fs,
                                                    const float* __restrict__ att_b,
                                                    const float* __restrict__ fc_w,
                                                    const float* __restrict__ fc_b,
                                                    float* __restrict__ out) {
    __shared__ float xs[64 * XSTR];
    __shared__ float wv[4][64];
    int t = threadIdx.x;
    int base = blockIdx.x * 64;

    if (t < 64) {
        int node = base + t;
        if (node < N) {
            float b = att_b[0] + fs[node];
            float g0 = 1.f / (1.f + __expf(-(S[0 * N + node] + b)));
            float g1 = 1.f / (1.f + __expf(-(S[1 * N + node] + b)));
            float g2 = 1.f / (1.f + __expf(-(S[2 * N + node] + b)));
            float g3 = 1.f / (1.f + __expf(-(S[3 * N + node] + b)));
            float m = fmaxf(fmaxf(g0, g1), fmaxf(g2, g3));
            float e0 = __expf(g0 - m), e1 = __expf(g1 - m);
            float e2 = __expf(g2 - m), e3 = __expf(g3 - m);
            float inv = 1.f / (e0 + e1 + e2 + e3);
            wv[0][t] = e0 * inv; wv[1][t] = e1 * inv;
            wv[2][t] = e2 * inv; wv[3][t] = e3 * inv;
        } else {
            wv[0][t] = 0.f; wv[1][t] = 0.f; wv[2][t] = 0.f; wv[3][t] = 0.f;
        }
    }
    __syncthreads();

#pragma unroll
    for (int qq = 0; qq < 4; ++qq) {
        int idx = qq * 256 + t;     // 0..1023
        int nl = idx >> 4;          // local node 0..63
        int d8 = idx & 15;          // uint4 (8-elem) index within row
        int node = base + nl;
        float o[8] = {0.f, 0.f, 0.f, 0.f, 0.f, 0.f, 0.f, 0.f};
        if (node < N) {
            float w0 = wv[0][nl], w1 = wv[1][nl], w2 = wv[2][nl], w3 = wv[3][nl];
            uint4 u0 = ((const uint4*)(hb + 0 * (size_t)NF + (size_t)node * NHID))[d8];
            uint4 u1 = ((const uint4*)(hb + 1 * (size_t)NF + (size_t)node * NHID))[d8];
            uint4 u2 = ((const uint4*)(hb + 2 * (size_t)NF + (size_t)node * NHID))[d8];
            uint4 u3 = ((const uint4*)(hb + 3 * (size_t)NF + (size_t)node * NHID))[d8];
            o[0] = w0 * bf16lo(u0.x) + w1 * bf16lo(u1.x) + w2 * bf16lo(u2.x) + w3 * bf16lo(u3.x);
            o[1] = w0 * bf16hi(u0.x) + w1 * bf16hi(u1.x) + w2 * bf16hi(u2.x) + w3 * bf16hi(u3.x);
            o[2] = w0 * bf16lo(u0.y) + w1 * bf16lo(u1.y) + w2 * bf16lo(u2.y) + w3 * bf16lo(u3.y);
            o[3] = w0 * bf16hi(u0.y) + w1 * bf16hi(u1.y) + w2 * bf16hi(u2.y) + w3 * bf16hi(u3.y);
            o[4] = w0 * bf16lo(u0.z) + w1 * bf16lo(u1.z) + w2 * bf16lo(u2.z) + w3 * bf16lo(u3.z);
            o[5] = w0 * bf16hi(u0.z) + w1 * bf16hi(u1.z) + w2 * bf16hi(u2.z) + w3 * bf16hi(u3.z);
            o[6] = w0 * bf16lo(u0.w) + w1 * bf16lo(u1.w) + w2 * bf16lo(u2.w) + w3 * bf16lo(u3.w);
            o[7] = w0 * bf16hi(u0.w) + w1 * bf16hi(u1.w) + w2 * bf16hi(u2.w) + w3 * bf16hi(u3.w);
        }
        float* xp = &xs[nl * XSTR + (d8 << 3)];
        *(float4*)xp       = make_float4(o[0], o[1], o[2], o[3]);
        *(float4*)(xp + 4) = make_float4(o[4], o[5], o[6], o[7]);
    }
    __syncthreads();

    int cq = t & 15;                     // col quad (active: cq<10)
    int rg = t >> 4;                     // row group: rows rg*4 .. rg*4+3
    int cb = (cq < 10) ? (cq << 2) : 36; // clamped col base: loads stay in-bounds
    float4 bias = *(const float4*)(fc_b + cb);
    float4 acc[4];
#pragma unroll
    for (int r = 0; r < 4; ++r) acc[r] = bias;
    for (int k4 = 0; k4 < NHID / 4; ++k4) {
        float4 w0 = *(const float4*)(fc_w + (size_t)(4 * k4 + 0) * NCLASS + cb);
        float4 w1 = *(const float4*)(fc_w + (size_t)(4 * k4 + 1) * NCLASS + cb);
        float4 w2 = *(const float4*)(fc_w + (size_t)(4 * k4 + 2) * NCLASS + cb);
        float4 w3 = *(const float4*)(fc_w + (size_t)(4 * k4 + 3) * NCLASS + cb);
#pragma unroll
        for (int r = 0; r < 4; ++r) {
            float4 xv = *(const float4*)&xs[(rg * 4 + r) * XSTR + (k4 << 2)];
            acc[r].x = fmaf(xv.x, w0.x, acc[r].x);
            acc[r].y = fmaf(xv.x, w0.y, acc[r].y);
            acc[r].z = fmaf(xv.x, w0.z, acc[r].z);
            acc[r].w = fmaf(xv.x, w0.w, acc[r].w);
            acc[r].x = fmaf(xv.y, w1.x, acc[r].x);
            acc[r].y = fmaf(xv.y, w1.y, acc[r].y);
            acc[r].z = fmaf(xv.y, w1.z, acc[r].z);
            acc[r].w = fmaf(xv.y, w1.w, acc[r].w);
            acc[r].x = fmaf(xv.z, w2.x, acc[r].x);
            acc[r].y = fmaf(xv.z, w2.y, acc[r].y);
            acc[r].z = fmaf(xv.z, w2.z, acc[r].z);
            acc[r].w = fmaf(xv.z, w2.w, acc[r].w);
            acc[r].x = fmaf(xv.w, w3.x, acc[r].x);
            acc[r].y = fmaf(xv.w, w3.y, acc[r].y);
            acc[r].z = fmaf(xv.w, w3.z, acc[r].z);
            acc[r].w = fmaf(xv.w, w3.w, acc[r].w);
        }
    }
#pragma unroll
    for (int r = 0; r < 4; ++r) {
        int nd = base + rg * 4 + r;
        float mloc = (cq < 10)
            ? fmaxf(fmaxf(acc[r].x, acc[r].y), fmaxf(acc[r].z, acc[r].w))
            : -INFINITY;
        float m = mloc;
        m = fmaxf(m, __shfl_xor(m, 1));
        m = fmaxf(m, __shfl_xor(m, 2));
        m = fmaxf(m, __shfl_xor(m, 4));
        m = fmaxf(m, __shfl_xor(m, 8));
        float sloc = (cq < 10)
            ? (__expf(acc[r].x - m) + __expf(acc[r].y - m) +
               __expf(acc[r].z - m) + __expf(acc[r].w - m))
            : 0.f;
        float s = sloc;
        s += __shfl_xor(s, 1);
        s += __shfl_xor(s, 2);
        s += __shfl_xor(s, 4);
        s += __shfl_xor(s, 8);
        float ls = m + logf(s);
        if (cq < 10 && nd < N) {
            float4 o;
            o.x = acc[r].x - ls;
            o.y = acc[r].y - ls;
            o.z = acc[r].z - ls;
            o.w = acc[r].w - ls;
            *(float4*)(out + (size_t)nd * NCLASS + cb) = o;
        }
    }
}

// ---------------- launch ----------------

extern "C" void kernel_launch(void* const* d_in, const int* in_sizes, int n_in,
                              void* d_out, int out_size, void* d_ws, size_t ws_size,
                              hipStream_t stream) {
    const float* features = (const float*)d_in[0];
    const int*   erow     = (const int*)d_in[1];
    const int*   ecol     = (const int*)d_in[2];
    const float* eval_    = (const float*)d_in[3];
    const float* Wg       = (const float*)d_in[4];
    const float* att_w    = (const float*)d_in[5];
    const float* att_b    = (const float*)d_in[6];
    const float* fc_w     = (const float*)d_in[7];
    const float* fc_b     = (const float*)d_in[8];
    float*       out      = (float*)d_out;

    // workspace layout (4-byte slots; ~99 MB -- far below the 137.6 MB proven bound)
    const size_t SLOTS = (size_t)NF            // tmp (f32 spmm result)
                       + 2 * (size_t)NF        // hbb: 4 buffers x NF bf16 = 2*NF slots... (see below)
                       + (size_t)NF / 2        // fb: NF bf16 = NF/2 slots
                       + 2 * (size_t)EVCAP     // ev (int2)
                       + (N + 4)               // rp
                       + N                     // cnt (reused as fs)
                       + 2 * NB                // bsum, boff
                       + 4 * (size_t)N;        // S
    if (ws_size < SLOTS * 4) return;  // readable failure instead of OOB crash

    float*          tmp  = (float*)d_ws;                         // NF f32
    unsigned short* hbb  = (unsigned short*)(tmp + NF);          // 4*NF bf16 (= 2*NF slots)
    unsigned short* fb   = hbb + 4 * (size_t)NF;                 // NF bf16 (= NF/2 slots)
    int2*           ev   = (int2*)(fb + NF);                     // EVCAP int2
    int*            rp   = (int*)(ev + EVCAP);                   // N+1 (+pad)
    int*            cnt  = rp + (N + 4);                         // N (hist/cursor/fs)
    int*            bsum = cnt + N;                              // NB
    int*            boff = bsum + NB;                            // NB
    float*          S    = (float*)(boff + NB);                  // 4*N hop scores
    float*          fs   = (float*)cnt;                          // alias after k_scatter

    // CSR build (rows padded to x4 with col=0,val=0)
    hipMemsetAsync(cnt, 0, N * sizeof(int), stream);
    hipMemsetAsync(ev, 0, EVCAP * sizeof(int2), stream);
    k_hist<<<(E + 255) / 256, 256, 0, stream>>>(erow, cnt);
    k_bsum<<<NB, 256, 0, stream>>>(cnt, bsum);
    k_scanb<<<1, 256, 0, stream>>>(bsum, boff);
    k_expand<<<NB, 256, 0, stream>>>(cnt, boff, rp);
    k_scatter<<<(E + 255) / 256, 256, 0, stream>>>(erow, ecol, eval_, cnt, ev);

    // feature score (f32) + bf16 feature copy for the gather
    k_fscore<<<(N * 64 + 255) / 256, 256, 0, stream>>>(features, att_w, fs);
    k_cvt<<<(NF / 4 + 255) / 256, 256, 0, stream>>>(features, fb);

    // hops: spmm gathers bf16, accumulates f32 into tmp; gemm writes bf16 h + scores
    const unsigned short* xb = fb;
    for (int i = 0; i < NUM_HOPS; ++i) {
        k_spmm<<<(N / 4) * 64 / 256, 256, 0, stream>>>(rp, ev, xb, tmp);
        k_gemm_relu<<<(N + GR - 1) / GR, 256, 0, stream>>>(tmp, Wg + (size_t)i * NHID * NHID,
                                                           att_w, hbb + (size_t)i * NF,
                                                           S + (size_t)i * N);
        xb = hbb + (size_t)i * NF;
    }

    // attention + fc + log_softmax (bf16 h input, f32 math)
    k_attn_final<<<(N + 63) / 64, 256, 0, stream>>>(hbb, S, fs, att_b, fc_w, fc_b, out);
}

// Round 14
// 450.119 us; speedup vs baseline: 1.4297x; 1.0353x over previous
//
#include <hip/hip_runtime.h>
#include <cmath>

#define N      50000
#define E      800000
#define NFEAT  128
#define NHID   128
#define NCLASS 40
#define NUM_HOPS 4
#define NF     (N * NHID)   // 6,400,000 elements per h buffer
#define GR     64           // GEMM rows per block
#define NB     ((N + 255) / 256)   // 196 scan blocks
#define EVCAP  (E + 3 * N)  // padded edge-array capacity (pad to multiple of 4)
#define XSTR   132          // LDS row stride in attn kernel (conflict break)

// bf16 helpers: RTNE pack of two floats into one dword; unpack by shift.
__device__ __forceinline__ unsigned bf16pack(float a, float b) {
    unsigned ua = __float_as_uint(a), ub = __float_as_uint(b);
    ua = (ua + 0x7fffu + ((ua >> 16) & 1u)) >> 16;
    ub = (ub + 0x7fffu + ((ub >> 16) & 1u)) >> 16;
    return ua | (ub << 16);
}
__device__ __forceinline__ float bf16lo(unsigned u) { return __uint_as_float(u << 16); }
__device__ __forceinline__ float bf16hi(unsigned u) { return __uint_as_float(u & 0xffff0000u); }

// ---------------- CSR build (rows padded to multiple of 4 edges) ----------------

__global__ void k_hist(const int* __restrict__ row, int* __restrict__ cnt) {
    int e = blockIdx.x * blockDim.x + threadIdx.x;
    if (e < E) atomicAdd(&cnt[row[e]], 1);
}

__global__ void k_bsum(const int* __restrict__ cnt, int* __restrict__ bsum) {
    int t = threadIdx.x;
    int i = blockIdx.x * 256 + t;
    int v = (i < N) ? ((cnt[i] + 3) & ~3) : 0;
    for (int off = 32; off; off >>= 1) v += __shfl_xor(v, off);
    __shared__ int ws[4];
    if ((t & 63) == 0) ws[t >> 6] = v;
    __syncthreads();
    if (t == 0) bsum[blockIdx.x] = ws[0] + ws[1] + ws[2] + ws[3];
}

__global__ void k_scanb(const int* __restrict__ bsum, int* __restrict__ boff) {
    __shared__ int ws[4];
    int t = threadIdx.x;
    int v = (t < NB) ? bsum[t] : 0;
    int lane = t & 63, w = t >> 6;
    int incl = v;
    for (int off = 1; off < 64; off <<= 1) {
        int u = __shfl_up(incl, off);
        if (lane >= off) incl += u;
    }
    if (lane == 63) ws[w] = incl;
    __syncthreads();
    int woff = 0;
    for (int k = 0; k < w; ++k) woff += ws[k];
    if (t < NB) boff[t] = incl - v + woff;
}

__global__ void k_expand(int* __restrict__ cnt, const int* __restrict__ boff,
                         int* __restrict__ rp) {
    __shared__ int ws[4];
    int t = threadIdx.x;
    int i = blockIdx.x * 256 + t;
    int pc = (i < N) ? ((cnt[i] + 3) & ~3) : 0;
    int lane = t & 63, w = t >> 6;
    int incl = pc;
    for (int off = 1; off < 64; off <<= 1) {
        int u = __shfl_up(incl, off);
        if (lane >= off) incl += u;
    }
    if (lane == 63) ws[w] = incl;
    __syncthreads();
    int woff = 0;
    for (int k = 0; k < w; ++k) woff += ws[k];
    int r = boff[blockIdx.x] + incl - pc + woff;
    if (i < N) {
        rp[i]  = r;
        cnt[i] = r;
        if (i == N - 1) rp[N] = r + pc;
    }
}

// Packed edge record: low 16 bits = col (N < 65536), high 16 bits = bf16(val).
// Pad entries are 0 -> col 0, val 0.0 (exact).
__global__ void k_scatter(const int* __restrict__ row, const int* __restrict__ col,
                          const float* __restrict__ val,
                          int* __restrict__ cur, unsigned* __restrict__ ev) {
    int e = blockIdx.x * blockDim.x + threadIdx.x;
    if (e < E) {
        int r = row[e];
        int p = atomicAdd(&cur[r], 1);
        unsigned v = __float_as_uint(val[e]);
        v = (v + 0x7fffu + ((v >> 16) & 1u)) & 0xffff0000u;   // RTNE bf16 in high half
        ev[p] = (unsigned)col[e] | v;
    }
}

// ---------------- SpMM: 4 rows per wave, bf16 x, packed 4B edges, f32 accumulate ----------------
// Each 16-lane quarter owns one row (256 B bf16 row = 16 lanes x 16 B -> one row
// per gather). 8 edges load as two uint4 (j is 4-aligned). Unroll-8 -> 8 KB of
// gathers in flight per wave. Same accumulation order as R13.

__global__ void k_spmm(const int* __restrict__ rp, const unsigned* __restrict__ ev,
                       const unsigned short* __restrict__ xb, float* __restrict__ y) {
    int wid  = (blockIdx.x * blockDim.x + threadIdx.x) >> 6;   // wave id
    if (wid >= N / 4) return;
    int lane = threadIdx.x & 63;
    int q  = lane >> 4;       // quarter 0..3
    int ql = lane & 15;       // lane within quarter
    int row = wid * 4 + q;
    int beg = rp[row], end = rp[row + 1];      // multiples of 4
    float a0 = 0.f, a1 = 0.f, a2 = 0.f, a3 = 0.f;
    float a4 = 0.f, a5 = 0.f, a6 = 0.f, a7 = 0.f;
    const uint4* xq = (const uint4*)xb;        // row r -> base index r*16
#define ACC8(g, v)                                                            \
    do {                                                                      \
        a0 = fmaf((v), bf16lo((g).x), a0); a1 = fmaf((v), bf16hi((g).x), a1); \
        a2 = fmaf((v), bf16lo((g).y), a2); a3 = fmaf((v), bf16hi((g).y), a3); \
        a4 = fmaf((v), bf16lo((g).z), a4); a5 = fmaf((v), bf16hi((g).z), a5); \
        a6 = fmaf((v), bf16lo((g).w), a6); a7 = fmaf((v), bf16hi((g).w), a7); \
    } while (0)
    int j = beg;
    for (; j + 8 <= end; j += 8) {
        uint4 p0 = *(const uint4*)(ev + j);
        uint4 p1 = *(const uint4*)(ev + j + 4);
        uint4 g0 = xq[(size_t)(p0.x & 0xffffu) * 16 + ql];
        uint4 g1 = xq[(size_t)(p0.y & 0xffffu) * 16 + ql];
        uint4 g2 = xq[(size_t)(p0.z & 0xffffu) * 16 + ql];
        uint4 g3 = xq[(size_t)(p0.w & 0xffffu) * 16 + ql];
        uint4 g4 = xq[(size_t)(p1.x & 0xffffu) * 16 + ql];
        uint4 g5 = xq[(size_t)(p1.y & 0xffffu) * 16 + ql];
        uint4 g6 = xq[(size_t)(p1.z & 0xffffu) * 16 + ql];
        uint4 g7 = xq[(size_t)(p1.w & 0xffffu) * 16 + ql];
        ACC8(g0, bf16hi(p0.x));
        ACC8(g1, bf16hi(p0.y));
        ACC8(g2, bf16hi(p0.z));
        ACC8(g3, bf16hi(p0.w));
        ACC8(g4, bf16hi(p1.x));
        ACC8(g5, bf16hi(p1.y));
        ACC8(g6, bf16hi(p1.z));
        ACC8(g7, bf16hi(p1.w));
    }
    if (j < end) {   // exactly 4 remain
        uint4 p0 = *(const uint4*)(ev + j);
        uint4 g0 = xq[(size_t)(p0.x & 0xffffu) * 16 + ql];
        uint4 g1 = xq[(size_t)(p0.y & 0xffffu) * 16 + ql];
        uint4 g2 = xq[(size_t)(p0.z & 0xffffu) * 16 + ql];
        uint4 g3 = xq[(size_t)(p0.w & 0xffffu) * 16 + ql];
        ACC8(g0, bf16hi(p0.x));
        ACC8(g1, bf16hi(p0.y));
        ACC8(g2, bf16hi(p0.z));
        ACC8(g3, bf16hi(p0.w));
    }
#undef ACC8
    float* yr = y + (size_t)row * NHID + ql * 8;
    *(float4*)yr       = make_float4(a0, a1, a2, a3);
    *(float4*)(yr + 4) = make_float4(a4, a5, a6, a7);
}

// ---------------- f32 -> bf16 convert (features) ----------------

__global__ void k_cvt(const float* __restrict__ f, unsigned short* __restrict__ fb) {
    int i = blockIdx.x * blockDim.x + threadIdx.x;   // one float4 per thread
    if (i >= NF / 4) return;
    float4 v = ((const float4*)f)[i];
    uint2 o;
    o.x = bf16pack(v.x, v.y);
    o.y = bf16pack(v.z, v.w);
    ((uint2*)fb)[i] = o;
}

// ---------------- GEMM (128x128 W) + ReLU + bf16 store + hop-score epilogue ----------------

__global__ __launch_bounds__(256) void k_gemm_relu(const float* __restrict__ x,
                                                   const float* __restrict__ W,
                                                   const float* __restrict__ att_w,
                                                   unsigned short* __restrict__ yb,
                                                   float* __restrict__ Sh) {
    __shared__ float xl[GR * NHID];
    int t = threadIdx.x;
    int rowbase = blockIdx.x * GR;
    int nrows = N - rowbase; if (nrows > GR) nrows = GR;
    {
        float4* xl4 = (float4*)xl;
        const float4* xg4 = (const float4*)(x + (size_t)rowbase * NHID);
        int maxq = nrows * (NHID / 4);
#pragma unroll
        for (int i = 0; i < (GR * NHID / 4) / 256; ++i) {
            int idx = i * 256 + t;
            if (idx < maxq) xl4[idx] = xg4[idx];
        }
    }
    __syncthreads();
    int cq = t & 31;          // col quad
    int rg = (t >> 5) << 3;   // row base (8 rows)
    float4 acc[8];
#pragma unroll
    for (int r = 0; r < 8; ++r) acc[r] = make_float4(0.f, 0.f, 0.f, 0.f);
    const float4* Wq = (const float4*)W;
    for (int k4 = 0; k4 < NHID / 4; ++k4) {
        float4 w0 = Wq[(4 * k4 + 0) * (NHID / 4) + cq];
        float4 w1 = Wq[(4 * k4 + 1) * (NHID / 4) + cq];
        float4 w2 = Wq[(4 * k4 + 2) * (NHID / 4) + cq];
        float4 w3 = Wq[(4 * k4 + 3) * (NHID / 4) + cq];
#pragma unroll
        for (int r = 0; r < 8; ++r) {
            float4 xv = *(const float4*)&xl[(rg + r) * NHID + 4 * k4];
            acc[r].x = fmaf(xv.x, w0.x, acc[r].x);
            acc[r].y = fmaf(xv.x, w0.y, acc[r].y);
            acc[r].z = fmaf(xv.x, w0.z, acc[r].z);
            acc[r].w = fmaf(xv.x, w0.w, acc[r].w);
            acc[r].x = fmaf(xv.y, w1.x, acc[r].x);
            acc[r].y = fmaf(xv.y, w1.y, acc[r].y);
            acc[r].z = fmaf(xv.y, w1.z, acc[r].z);
            acc[r].w = fmaf(xv.y, w1.w, acc[r].w);
            acc[r].x = fmaf(xv.z, w2.x, acc[r].x);
            acc[r].y = fmaf(xv.z, w2.y, acc[r].y);
            acc[r].z = fmaf(xv.z, w2.z, acc[r].z);
            acc[r].w = fmaf(xv.z, w2.w, acc[r].w);
            acc[r].x = fmaf(xv.w, w3.x, acc[r].x);
            acc[r].y = fmaf(xv.w, w3.y, acc[r].y);
            acc[r].z = fmaf(xv.w, w3.z, acc[r].z);
            acc[r].w = fmaf(xv.w, w3.w, acc[r].w);
        }
    }
#pragma unroll
    for (int r = 0; r < 8; ++r) {
        acc[r].x = fmaxf(acc[r].x, 0.f);
        acc[r].y = fmaxf(acc[r].y, 0.f);
        acc[r].z = fmaxf(acc[r].z, 0.f);
        acc[r].w = fmaxf(acc[r].w, 0.f);
        int row = rowbase + rg + r;
        if (row < N) {
            uint2 o;
            o.x = bf16pack(acc[r].x, acc[r].y);
            o.y = bf16pack(acc[r].z, acc[r].w);
            *(uint2*)(yb + (size_t)row * NHID + (cq << 2)) = o;
        }
    }
    // ---- hop-score epilogue (pre-rounding f32 values) ----
    float4 whv = ((const float4*)att_w)[cq];
#pragma unroll
    for (int r = 0; r < 8; ++r) {
        float p = acc[r].x * whv.x;
        p = fmaf(acc[r].y, whv.y, p);
        p = fmaf(acc[r].z, whv.z, p);
        p = fmaf(acc[r].w, whv.w, p);
        p += __shfl_xor(p, 1);
        p += __shfl_xor(p, 2);
        p += __shfl_xor(p, 4);
        p += __shfl_xor(p, 8);
        p += __shfl_xor(p, 16);
        int row = rowbase + rg + r;
        if (cq == 0 && row < N) Sh[row] = p;
    }
}

// ---------------- Feature score: fs[node] = f[node] . w_f (f32 features) ----------------

__global__ void k_fscore(const float* __restrict__ f, const float* __restrict__ att_w,
                         float* __restrict__ fs) {
    int node = (blockIdx.x * blockDim.x + threadIdx.x) >> 6;
    if (node >= N) return;
    int lane = threadIdx.x & 63;
    const float2 wf = ((const float2*)(att_w + NHID))[lane];
    const float2 fv = ((const float2*)(f + (size_t)node * NFEAT))[lane];
    float s = fv.x * wf.x + fv.y * wf.y;
    for (int off = 32; off; off >>= 1) s += __shfl_xor(s, off);
    if (lane == 0) fs[node] = s;
}

// ---------------- Attention + output head (64 nodes/block, bf16 h input) ----------------

__global__ __launch_bounds__(256) void k_attn_final(const unsigned short* __restrict__ hb,
                                                    const float* __restrict__ S,
                                                    const float* __restrict__ fs,
                                                    const float* __restrict__ att_b,
                                                    const float* __restrict__ fc_w,
                                                    const float* __restrict__ fc_b,
                                                    float* __restrict__ out) {
    __shared__ float xs[64 * XSTR];
    __shared__ float wv[4][64];
    int t = threadIdx.x;
    int base = blockIdx.x * 64;

    if (t < 64) {
        int node = base + t;
        if (node < N) {
            float b = att_b[0] + fs[node];
            float g0 = 1.f / (1.f + __expf(-(S[0 * N + node] + b)));
            float g1 = 1.f / (1.f + __expf(-(S[1 * N + node] + b)));
            float g2 = 1.f / (1.f + __expf(-(S[2 * N + node] + b)));
            float g3 = 1.f / (1.f + __expf(-(S[3 * N + node] + b)));
            float m = fmaxf(fmaxf(g0, g1), fmaxf(g2, g3));
            float e0 = __expf(g0 - m), e1 = __expf(g1 - m);
            float e2 = __expf(g2 - m), e3 = __expf(g3 - m);
            float inv = 1.f / (e0 + e1 + e2 + e3);
            wv[0][t] = e0 * inv; wv[1][t] = e1 * inv;
            wv[2][t] = e2 * inv; wv[3][t] = e3 * inv;
        } else {
            wv[0][t] = 0.f; wv[1][t] = 0.f; wv[2][t] = 0.f; wv[3][t] = 0.f;
        }
    }
    __syncthreads();

#pragma unroll
    for (int qq = 0; qq < 4; ++qq) {
        int idx = qq * 256 + t;     // 0..1023
        int nl = idx >> 4;          // local node 0..63
        int d8 = idx & 15;          // uint4 (8-elem) index within row
        int node = base + nl;
        float o[8] = {0.f, 0.f, 0.f, 0.f, 0.f, 0.f, 0.f, 0.f};
        if (node < N) {
            float w0 = wv[0][nl], w1 = wv[1][nl], w2 = wv[2][nl], w3 = wv[3][nl];
            uint4 u0 = ((const uint4*)(hb + 0 * (size_t)NF + (size_t)node * NHID))[d8];
            uint4 u1 = ((const uint4*)(hb + 1 * (size_t)NF + (size_t)node * NHID))[d8];
            uint4 u2 = ((const uint4*)(hb + 2 * (size_t)NF + (size_t)node * NHID))[d8];
            uint4 u3 = ((const uint4*)(hb + 3 * (size_t)NF + (size_t)node * NHID))[d8];
            o[0] = w0 * bf16lo(u0.x) + w1 * bf16lo(u1.x) + w2 * bf16lo(u2.x) + w3 * bf16lo(u3.x);
            o[1] = w0 * bf16hi(u0.x) + w1 * bf16hi(u1.x) + w2 * bf16hi(u2.x) + w3 * bf16hi(u3.x);
            o[2] = w0 * bf16lo(u0.y) + w1 * bf16lo(u1.y) + w2 * bf16lo(u2.y) + w3 * bf16lo(u3.y);
            o[3] = w0 * bf16hi(u0.y) + w1 * bf16hi(u1.y) + w2 * bf16hi(u2.y) + w3 * bf16hi(u3.y);
            o[4] = w0 * bf16lo(u0.z) + w1 * bf16lo(u1.z) + w2 * bf16lo(u2.z) + w3 * bf16lo(u3.z);
            o[5] = w0 * bf16hi(u0.z) + w1 * bf16hi(u1.z) + w2 * bf16hi(u2.z) + w3 * bf16hi(u3.z);
            o[6] = w0 * bf16lo(u0.w) + w1 * bf16lo(u1.w) + w2 * bf16lo(u2.w) + w3 * bf16lo(u3.w);
            o[7] = w0 * bf16hi(u0.w) + w1 * bf16hi(u1.w) + w2 * bf16hi(u2.w) + w3 * bf16hi(u3.w);
        }
        float* xp = &xs[nl * XSTR + (d8 << 3)];
        *(float4*)xp       = make_float4(o[0], o[1], o[2], o[3]);
        *(float4*)(xp + 4) = make_float4(o[4], o[5], o[6], o[7]);
    }
    __syncthreads();

    int cq = t & 15;                     // col quad (active: cq<10)
    int rg = t >> 4;                     // row group: rows rg*4 .. rg*4+3
    int cb = (cq < 10) ? (cq << 2) : 36; // clamped col base: loads stay in-bounds
    float4 bias = *(const float4*)(fc_b + cb);
    float4 acc[4];
#pragma unroll
    for (int r = 0; r < 4; ++r) acc[r] = bias;
    for (int k4 = 0; k4 < NHID / 4; ++k4) {
        float4 w0 = *(const float4*)(fc_w + (size_t)(4 * k4 + 0) * NCLASS + cb);
        float4 w1 = *(const float4*)(fc_w + (size_t)(4 * k4 + 1) * NCLASS + cb);
        float4 w2 = *(const float4*)(fc_w + (size_t)(4 * k4 + 2) * NCLASS + cb);
        float4 w3 = *(const float4*)(fc_w + (size_t)(4 * k4 + 3) * NCLASS + cb);
#pragma unroll
        for (int r = 0; r < 4; ++r) {
            float4 xv = *(const float4*)&xs[(rg * 4 + r) * XSTR + (k4 << 2)];
            acc[r].x = fmaf(xv.x, w0.x, acc[r].x);
            acc[r].y = fmaf(xv.x, w0.y, acc[r].y);
            acc[r].z = fmaf(xv.x, w0.z, acc[r].z);
            acc[r].w = fmaf(xv.x, w0.w, acc[r].w);
            acc[r].x = fmaf(xv.y, w1.x, acc[r].x);
            acc[r].y = fmaf(xv.y, w1.y, acc[r].y);
            acc[r].z = fmaf(xv.y, w1.z, acc[r].z);
            acc[r].w = fmaf(xv.y, w1.w, acc[r].w);
            acc[r].x = fmaf(xv.z, w2.x, acc[r].x);
            acc[r].y = fmaf(xv.z, w2.y, acc[r].y);
            acc[r].z = fmaf(xv.z, w2.z, acc[r].z);
            acc[r].w = fmaf(xv.z, w2.w, acc[r].w);
            acc[r].x = fmaf(xv.w, w3.x, acc[r].x);
            acc[r].y = fmaf(xv.w, w3.y, acc[r].y);
            acc[r].z = fmaf(xv.w, w3.z, acc[r].z);
            acc[r].w = fmaf(xv.w, w3.w, acc[r].w);
        }
    }
#pragma unroll
    for (int r = 0; r < 4; ++r) {
        int nd = base + rg * 4 + r;
        float mloc = (cq < 10)
            ? fmaxf(fmaxf(acc[r].x, acc[r].y), fmaxf(acc[r].z, acc[r].w))
            : -INFINITY;
        float m = mloc;
        m = fmaxf(m, __shfl_xor(m, 1));
        m = fmaxf(m, __shfl_xor(m, 2));
        m = fmaxf(m, __shfl_xor(m, 4));
        m = fmaxf(m, __shfl_xor(m, 8));
        float sloc = (cq < 10)
            ? (__expf(acc[r].x - m) + __expf(acc[r].y - m) +
               __expf(acc[r].z - m) + __expf(acc[r].w - m))
            : 0.f;
        float s = sloc;
        s += __shfl_xor(s, 1);
        s += __shfl_xor(s, 2);
        s += __shfl_xor(s, 4);
        s += __shfl_xor(s, 8);
        float ls = m + logf(s);
        if (cq < 10 && nd < N) {
            float4 o;
            o.x = acc[r].x - ls;
            o.y = acc[r].y - ls;
            o.z = acc[r].z - ls;
            o.w = acc[r].w - ls;
            *(float4*)(out + (size_t)nd * NCLASS + cb) = o;
        }
    }
}

// ---------------- launch ----------------

extern "C" void kernel_launch(void* const* d_in, const int* in_sizes, int n_in,
                              void* d_out, int out_size, void* d_ws, size_t ws_size,
                              hipStream_t stream) {
    const float* features = (const float*)d_in[0];
    const int*   erow     = (const int*)d_in[1];
    const int*   ecol     = (const int*)d_in[2];
    const float* eval_    = (const float*)d_in[3];
    const float* Wg       = (const float*)d_in[4];
    const float* att_w    = (const float*)d_in[5];
    const float* att_b    = (const float*)d_in[6];
    const float* fc_w     = (const float*)d_in[7];
    const float* fc_b     = (const float*)d_in[8];
    float*       out      = (float*)d_out;

    // workspace layout (4-byte slots; ~95 MB)
    const size_t SLOTS = (size_t)NF            // tmp (f32 spmm result)
                       + 2 * (size_t)NF        // hbb: 4 x NF bf16
                       + (size_t)NF / 2        // fb: NF bf16
                       + (size_t)EVCAP         // ev (packed u32)
                       + (N + 4)               // rp
                       + N                     // cnt (reused as fs)
                       + 2 * NB                // bsum, boff
                       + 4 * (size_t)N;        // S
    if (ws_size < SLOTS * 4) return;  // readable failure instead of OOB crash

    float*          tmp  = (float*)d_ws;                         // NF f32
    unsigned short* hbb  = (unsigned short*)(tmp + NF);          // 4*NF bf16
    unsigned short* fb   = hbb + 4 * (size_t)NF;                 // NF bf16
    unsigned*       ev   = (unsigned*)(fb + NF);                 // EVCAP u32
    int*            rp   = (int*)(ev + EVCAP);                   // N+1 (+pad)
    int*            cnt  = rp + (N + 4);                         // N (hist/cursor/fs)
    int*            bsum = cnt + N;                              // NB
    int*            boff = bsum + NB;                            // NB
    float*          S    = (float*)(boff + NB);                  // 4*N hop scores
    float*          fs   = (float*)cnt;                          // alias after k_scatter

    // CSR build (rows padded to x4 with packed-zero edges)
    hipMemsetAsync(cnt, 0, N * sizeof(int), stream);
    hipMemsetAsync(ev, 0, EVCAP * sizeof(unsigned), stream);
    k_hist<<<(E + 255) / 256, 256, 0, stream>>>(erow, cnt);
    k_bsum<<<NB, 256, 0, stream>>>(cnt, bsum);
    k_scanb<<<1, 256, 0, stream>>>(bsum, boff);
    k_expand<<<NB, 256, 0, stream>>>(cnt, boff, rp);
    k_scatter<<<(E + 255) / 256, 256, 0, stream>>>(erow, ecol, eval_, cnt, ev);

    // feature score (f32) + bf16 feature copy for the gather
    k_fscore<<<(N * 64 + 255) / 256, 256, 0, stream>>>(features, att_w, fs);
    k_cvt<<<(NF / 4 + 255) / 256, 256, 0, stream>>>(features, fb);

    // hops: spmm gathers bf16 x + packed edges, accumulates f32; gemm writes bf16 h + scores
    const unsigned short* xb = fb;
    for (int i = 0; i < NUM_HOPS; ++i) {
        k_spmm<<<(N / 4) * 64 / 256, 256, 0, stream>>>(rp, ev, xb, tmp);
        k_gemm_relu<<<(N + GR - 1) / GR, 256, 0, stream>>>(tmp, Wg + (size_t)i * NHID * NHID,
                                                           att_w, hbb + (size_t)i * NF,
                                                           S + (size_t)i * N);
        xb = hbb + (size_t)i * NF;
    }

    // attention + fc + log_softmax (bf16 h input, f32 math)
    k_attn_final<<<(N + 63) / 64, 256, 0, stream>>>(hbb, S, fs, att_b, fc_w, fc_b, out);
}

// Round 15
// 415.525 us; speedup vs baseline: 1.5488x; 1.0833x over previous
//
#include <hip/hip_runtime.h>
#include <cmath>

#define N      50000
#define E      800000
#define NFEAT  128
#define NHID   128
#define NCLASS 40
#define NUM_HOPS 4
#define NF     (N * NHID)   // 6,400,000 elements per h buffer
#define NB     ((N + 255) / 256)   // 196 scan blocks
#define EVCAP  (E + 3 * N)  // padded edge-array capacity (pad to multiple of 4)
#define XSTR   132          // LDS row stride in attn kernel (conflict break)

typedef __attribute__((ext_vector_type(8))) short bf16x8;   // 8 bf16 in 4 VGPRs
typedef __attribute__((ext_vector_type(4))) float f32x4;

// bf16 helpers (RTNE)
__device__ __forceinline__ unsigned bf16pack(float a, float b) {
    unsigned ua = __float_as_uint(a), ub = __float_as_uint(b);
    ua = (ua + 0x7fffu + ((ua >> 16) & 1u)) >> 16;
    ub = (ub + 0x7fffu + ((ub >> 16) & 1u)) >> 16;
    return ua | (ub << 16);
}
__device__ __forceinline__ unsigned short bf16s(float x) {
    unsigned u = __float_as_uint(x);
    u = (u + 0x7fffu + ((u >> 16) & 1u)) >> 16;
    return (unsigned short)u;
}
__device__ __forceinline__ float bf16lo(unsigned u) { return __uint_as_float(u << 16); }
__device__ __forceinline__ float bf16hi(unsigned u) { return __uint_as_float(u & 0xffff0000u); }

// ---------------- CSR build (rows padded to multiple of 4 edges) ----------------

__global__ void k_hist(const int* __restrict__ row, int* __restrict__ cnt) {
    int e = blockIdx.x * blockDim.x + threadIdx.x;
    if (e < E) atomicAdd(&cnt[row[e]], 1);
}

__global__ void k_bsum(const int* __restrict__ cnt, int* __restrict__ bsum) {
    int t = threadIdx.x;
    int i = blockIdx.x * 256 + t;
    int v = (i < N) ? ((cnt[i] + 3) & ~3) : 0;
    for (int off = 32; off; off >>= 1) v += __shfl_xor(v, off);
    __shared__ int ws[4];
    if ((t & 63) == 0) ws[t >> 6] = v;
    __syncthreads();
    if (t == 0) bsum[blockIdx.x] = ws[0] + ws[1] + ws[2] + ws[3];
}

__global__ void k_scanb(const int* __restrict__ bsum, int* __restrict__ boff) {
    __shared__ int ws[4];
    int t = threadIdx.x;
    int v = (t < NB) ? bsum[t] : 0;
    int lane = t & 63, w = t >> 6;
    int incl = v;
    for (int off = 1; off < 64; off <<= 1) {
        int u = __shfl_up(incl, off);
        if (lane >= off) incl += u;
    }
    if (lane == 63) ws[w] = incl;
    __syncthreads();
    int woff = 0;
    for (int k = 0; k < w; ++k) woff += ws[k];
    if (t < NB) boff[t] = incl - v + woff;
}

__global__ void k_expand(int* __restrict__ cnt, const int* __restrict__ boff,
                         int* __restrict__ rp) {
    __shared__ int ws[4];
    int t = threadIdx.x;
    int i = blockIdx.x * 256 + t;
    int pc = (i < N) ? ((cnt[i] + 3) & ~3) : 0;
    int lane = t & 63, w = t >> 6;
    int incl = pc;
    for (int off = 1; off < 64; off <<= 1) {
        int u = __shfl_up(incl, off);
        if (lane >= off) incl += u;
    }
    if (lane == 63) ws[w] = incl;
    __syncthreads();
    int woff = 0;
    for (int k = 0; k < w; ++k) woff += ws[k];
    int r = boff[blockIdx.x] + incl - pc + woff;
    if (i < N) {
        rp[i]  = r;
        cnt[i] = r;
        if (i == N - 1) rp[N] = r + pc;
    }
}

// Packed edge: low 16 bits = col (N < 65536), high 16 = bf16(val). Pads are 0.
__global__ void k_scatter(const int* __restrict__ row, const int* __restrict__ col,
                          const float* __restrict__ val,
                          int* __restrict__ cur, unsigned* __restrict__ ev) {
    int e = blockIdx.x * blockDim.x + threadIdx.x;
    if (e < E) {
        int r = row[e];
        int p = atomicAdd(&cur[r], 1);
        unsigned v = __float_as_uint(val[e]);
        v = (v + 0x7fffu + ((v >> 16) & 1u)) & 0xffff0000u;
        ev[p] = (unsigned)col[e] | v;
    }
}

// ---------------- SpMM: 4 rows per wave, bf16 x, packed edges, f32 acc, bf16 out ----------------

__global__ void k_spmm(const int* __restrict__ rp, const unsigned* __restrict__ ev,
                       const unsigned short* __restrict__ xb,
                       unsigned short* __restrict__ y) {
    int wid  = (blockIdx.x * blockDim.x + threadIdx.x) >> 6;   // wave id
    if (wid >= N / 4) return;
    int lane = threadIdx.x & 63;
    int q  = lane >> 4;       // quarter 0..3
    int ql = lane & 15;       // lane within quarter
    int row = wid * 4 + q;
    int beg = rp[row], end = rp[row + 1];      // multiples of 4
    float a0 = 0.f, a1 = 0.f, a2 = 0.f, a3 = 0.f;
    float a4 = 0.f, a5 = 0.f, a6 = 0.f, a7 = 0.f;
    const uint4* xq = (const uint4*)xb;        // row r -> base index r*16
#define ACC8(g, v)                                                            \
    do {                                                                      \
        a0 = fmaf((v), bf16lo((g).x), a0); a1 = fmaf((v), bf16hi((g).x), a1); \
        a2 = fmaf((v), bf16lo((g).y), a2); a3 = fmaf((v), bf16hi((g).y), a3); \
        a4 = fmaf((v), bf16lo((g).z), a4); a5 = fmaf((v), bf16hi((g).z), a5); \
        a6 = fmaf((v), bf16lo((g).w), a6); a7 = fmaf((v), bf16hi((g).w), a7); \
    } while (0)
    int j = beg;
    for (; j + 8 <= end; j += 8) {
        uint4 p0 = *(const uint4*)(ev + j);
        uint4 p1 = *(const uint4*)(ev + j + 4);
        uint4 g0 = xq[(size_t)(p0.x & 0xffffu) * 16 + ql];
        uint4 g1 = xq[(size_t)(p0.y & 0xffffu) * 16 + ql];
        uint4 g2 = xq[(size_t)(p0.z & 0xffffu) * 16 + ql];
        uint4 g3 = xq[(size_t)(p0.w & 0xffffu) * 16 + ql];
        uint4 g4 = xq[(size_t)(p1.x & 0xffffu) * 16 + ql];
        uint4 g5 = xq[(size_t)(p1.y & 0xffffu) * 16 + ql];
        uint4 g6 = xq[(size_t)(p1.z & 0xffffu) * 16 + ql];
        uint4 g7 = xq[(size_t)(p1.w & 0xffffu) * 16 + ql];
        ACC8(g0, bf16hi(p0.x));
        ACC8(g1, bf16hi(p0.y));
        ACC8(g2, bf16hi(p0.z));
        ACC8(g3, bf16hi(p0.w));
        ACC8(g4, bf16hi(p1.x));
        ACC8(g5, bf16hi(p1.y));
        ACC8(g6, bf16hi(p1.z));
        ACC8(g7, bf16hi(p1.w));
    }
    if (j < end) {   // exactly 4 remain
        uint4 p0 = *(const uint4*)(ev + j);
        uint4 g0 = xq[(size_t)(p0.x & 0xffffu) * 16 + ql];
        uint4 g1 = xq[(size_t)(p0.y & 0xffffu) * 16 + ql];
        uint4 g2 = xq[(size_t)(p0.z & 0xffffu) * 16 + ql];
        uint4 g3 = xq[(size_t)(p0.w & 0xffffu) * 16 + ql];
        ACC8(g0, bf16hi(p0.x));
        ACC8(g1, bf16hi(p0.y));
        ACC8(g2, bf16hi(p0.z));
        ACC8(g3, bf16hi(p0.w));
    }
#undef ACC8
    uint4 o;
    o.x = bf16pack(a0, a1);
    o.y = bf16pack(a2, a3);
    o.z = bf16pack(a4, a5);
    o.w = bf16pack(a6, a7);
    ((uint4*)(y + (size_t)row * NHID))[ql] = o;
}

// ---------------- f32 -> bf16 converts ----------------

__global__ void k_cvt(const float* __restrict__ f, unsigned short* __restrict__ fb) {
    int i = blockIdx.x * blockDim.x + threadIdx.x;   // one float4 per thread
    if (i >= NF / 4) return;
    float4 v = ((const float4*)f)[i];
    uint2 o;
    o.x = bf16pack(v.x, v.y);
    o.y = bf16pack(v.z, v.w);
    ((uint2*)fb)[i] = o;
}

// W (4 x 128 x 128, [hop][k][n]) -> transposed bf16 Wbt [hop][n][k]
__global__ void k_cvt_w(const float* __restrict__ Wg, unsigned short* __restrict__ Wbt) {
    int idx = blockIdx.x * blockDim.x + threadIdx.x;
    if (idx >= NUM_HOPS * NHID * NHID) return;
    int i = idx >> 14;            // hop
    int rem = idx & 16383;
    int n = rem >> 7;             // out row (col of W)
    int k = rem & 127;            // out col (row of W)
    Wbt[idx] = bf16s(Wg[(i << 14) + k * NHID + n]);
}

// ---------------- GEMM via MFMA 16x16x32 bf16: h = relu(tmp @ W), + hop score ----------------
// Block = 4 waves x 16 rows = 64 rows. Wave: 8 n-tiles x 4 k-steps = 32 MFMA.
// A-frag: lane holds A[m=lane&15][k=quad*8+j] -> 16B contiguous from tmpb (each row read once).
// B-frag: lane holds B[k=quad*8+j][n=lane&15] -> 16B contiguous from Wbt (L2-hot).
// C/D: col=lane&15, row=quad*4+reg (verified mapping).

__global__ __launch_bounds__(256) void k_gemm(const unsigned short* __restrict__ tmpb,
                                              const unsigned short* __restrict__ Wbt,
                                              const float* __restrict__ att_w,
                                              unsigned short* __restrict__ yb,
                                              float* __restrict__ Sh) {
    int t = threadIdx.x;
    int w = t >> 6;
    int lane = t & 63;
    int quad = lane >> 4;
    int l15 = lane & 15;
    int rowb = blockIdx.x * 64 + w * 16;      // wave's 16-row base

    // A fragments for the 4 k-steps (row m = rowb + l15; OOB rows read ws garbage, stores guarded)
    bf16x8 af[4];
#pragma unroll
    for (int s = 0; s < 4; ++s) {
        uint4 ua = *(const uint4*)(tmpb + ((size_t)(rowb + l15) * NHID + s * 32 + quad * 8));
        af[s] = __builtin_bit_cast(bf16x8, ua);
    }

    f32x4 acc[8];
#pragma unroll
    for (int nt = 0; nt < 8; ++nt) acc[nt] = (f32x4){0.f, 0.f, 0.f, 0.f};

#pragma unroll
    for (int nt = 0; nt < 8; ++nt) {
#pragma unroll
        for (int s = 0; s < 4; ++s) {
            uint4 ub = *(const uint4*)(Wbt + ((size_t)(nt * 16 + l15) * NHID + s * 32 + quad * 8));
            bf16x8 bfv = __builtin_bit_cast(bf16x8, ub);
            acc[nt] = __builtin_amdgcn_mfma_f32_16x16x32_bf16(af[s], bfv, acc[nt], 0, 0, 0);
        }
    }

    // per-lane w_h values for the 8 cols this lane owns
    float whl[8];
#pragma unroll
    for (int nt = 0; nt < 8; ++nt) whl[nt] = att_w[nt * 16 + l15];

    float scr[4] = {0.f, 0.f, 0.f, 0.f};
#pragma unroll
    for (int nt = 0; nt < 8; ++nt) {
#pragma unroll
        for (int r = 0; r < 4; ++r) {
            float v = fmaxf(acc[nt][r], 0.f);
            scr[r] = fmaf(v, whl[nt], scr[r]);
            int grow = rowb + quad * 4 + r;
            if (grow < N)
                yb[(size_t)grow * NHID + nt * 16 + l15] = bf16s(v);
        }
    }
    // score reduction across the 16 col-lanes (stays within quad)
#pragma unroll
    for (int r = 0; r < 4; ++r) {
        float p = scr[r];
        p += __shfl_xor(p, 1);
        p += __shfl_xor(p, 2);
        p += __shfl_xor(p, 4);
        p += __shfl_xor(p, 8);
        int grow = rowb + quad * 4 + r;
        if (l15 == 0 && grow < N) Sh[grow] = p;
    }
}

// ---------------- Feature score: fs[node] = f[node] . w_f (f32 features) ----------------

__global__ void k_fscore(const float* __restrict__ f, const float* __restrict__ att_w,
                         float* __restrict__ fs) {
    int node = (blockIdx.x * blockDim.x + threadIdx.x) >> 6;
    if (node >= N) return;
    int lane = threadIdx.x & 63;
    const float2 wf = ((const float2*)(att_w + NHID))[lane];
    const float2 fv = ((const float2*)(f + (size_t)node * NFEAT))[lane];
    float s = fv.x * wf.x + fv.y * wf.y;
    for (int off = 32; off; off >>= 1) s += __shfl_xor(s, off);
    if (lane == 0) fs[node] = s;
}

// ---------------- Attention + output head (64 nodes/block, bf16 h input) ----------------

__global__ __launch_bounds__(256) void k_attn_final(const unsigned short* __restrict__ hb,
                                                    const float* __restrict__ S,
                                                    const float* __restrict__ fs,
                                                    const float* __restrict__ att_b,
                                                    const float* __restrict__ fc_w,
                                                    const float* __restrict__ fc_b,
                                                    float* __restrict__ out) {
    __shared__ float xs[64 * XSTR];
    __shared__ float wv[4][64];
    int t = threadIdx.x;
    int base = blockIdx.x * 64;

    if (t < 64) {
        int node = base + t;
        if (node < N) {
            float b = att_b[0] + fs[node];
            float g0 = 1.f / (1.f + __expf(-(S[0 * N + node] + b)));
            float g1 = 1.f / (1.f + __expf(-(S[1 * N + node] + b)));
            float g2 = 1.f / (1.f + __expf(-(S[2 * N + node] + b)));
            float g3 = 1.f / (1.f + __expf(-(S[3 * N + node] + b)));
            float m = fmaxf(fmaxf(g0, g1), fmaxf(g2, g3));
            float e0 = __expf(g0 - m), e1 = __expf(g1 - m);
            float e2 = __expf(g2 - m), e3 = __expf(g3 - m);
            float inv = 1.f / (e0 + e1 + e2 + e3);
            wv[0][t] = e0 * inv; wv[1][t] = e1 * inv;
            wv[2][t] = e2 * inv; wv[3][t] = e3 * inv;
        } else {
            wv[0][t] = 0.f; wv[1][t] = 0.f; wv[2][t] = 0.f; wv[3][t] = 0.f;
        }
    }
    __syncthreads();

#pragma unroll
    for (int qq = 0; qq < 4; ++qq) {
        int idx = qq * 256 + t;     // 0..1023
        int nl = idx >> 4;          // local node 0..63
        int d8 = idx & 15;          // uint4 (8-elem) index within row
        int node = base + nl;
        float o[8] = {0.f, 0.f, 0.f, 0.f, 0.f, 0.f, 0.f, 0.f};
        if (node < N) {
            float w0 = wv[0][nl], w1 = wv[1][nl], w2 = wv[2][nl], w3 = wv[3][nl];
            uint4 u0 = ((const uint4*)(hb + 0 * (size_t)NF + (size_t)node * NHID))[d8];
            uint4 u1 = ((const uint4*)(hb + 1 * (size_t)NF + (size_t)node * NHID))[d8];
            uint4 u2 = ((const uint4*)(hb + 2 * (size_t)NF + (size_t)node * NHID))[d8];
            uint4 u3 = ((const uint4*)(hb + 3 * (size_t)NF + (size_t)node * NHID))[d8];
            o[0] = w0 * bf16lo(u0.x) + w1 * bf16lo(u1.x) + w2 * bf16lo(u2.x) + w3 * bf16lo(u3.x);
            o[1] = w0 * bf16hi(u0.x) + w1 * bf16hi(u1.x) + w2 * bf16hi(u2.x) + w3 * bf16hi(u3.x);
            o[2] = w0 * bf16lo(u0.y) + w1 * bf16lo(u1.y) + w2 * bf16lo(u2.y) + w3 * bf16lo(u3.y);
            o[3] = w0 * bf16hi(u0.y) + w1 * bf16hi(u1.y) + w2 * bf16hi(u2.y) + w3 * bf16hi(u3.y);
            o[4] = w0 * bf16lo(u0.z) + w1 * bf16lo(u1.z) + w2 * bf16lo(u2.z) + w3 * bf16lo(u3.z);
            o[5] = w0 * bf16hi(u0.z) + w1 * bf16hi(u1.z) + w2 * bf16hi(u2.z) + w3 * bf16hi(u3.z);
            o[6] = w0 * bf16lo(u0.w) + w1 * bf16lo(u1.w) + w2 * bf16lo(u2.w) + w3 * bf16lo(u3.w);
            o[7] = w0 * bf16hi(u0.w) + w1 * bf16hi(u1.w) + w2 * bf16hi(u2.w) + w3 * bf16hi(u3.w);
        }
        float* xp = &xs[nl * XSTR + (d8 << 3)];
        *(float4*)xp       = make_float4(o[0], o[1], o[2], o[3]);
        *(float4*)(xp + 4) = make_float4(o[4], o[5], o[6], o[7]);
    }
    __syncthreads();

    int cq = t & 15;                     // col quad (active: cq<10)
    int rg = t >> 4;                     // row group: rows rg*4 .. rg*4+3
    int cb = (cq < 10) ? (cq << 2) : 36; // clamped col base: loads stay in-bounds
    float4 bias = *(const float4*)(fc_b + cb);
    float4 acc[4];
#pragma unroll
    for (int r = 0; r < 4; ++r) acc[r] = bias;
    for (int k4 = 0; k4 < NHID / 4; ++k4) {
        float4 w0 = *(const float4*)(fc_w + (size_t)(4 * k4 + 0) * NCLASS + cb);
        float4 w1 = *(const float4*)(fc_w + (size_t)(4 * k4 + 1) * NCLASS + cb);
        float4 w2 = *(const float4*)(fc_w + (size_t)(4 * k4 + 2) * NCLASS + cb);
        float4 w3 = *(const float4*)(fc_w + (size_t)(4 * k4 + 3) * NCLASS + cb);
#pragma unroll
        for (int r = 0; r < 4; ++r) {
            float4 xv = *(const float4*)&xs[(rg * 4 + r) * XSTR + (k4 << 2)];
            acc[r].x = fmaf(xv.x, w0.x, acc[r].x);
            acc[r].y = fmaf(xv.x, w0.y, acc[r].y);
            acc[r].z = fmaf(xv.x, w0.z, acc[r].z);
            acc[r].w = fmaf(xv.x, w0.w, acc[r].w);
            acc[r].x = fmaf(xv.y, w1.x, acc[r].x);
            acc[r].y = fmaf(xv.y, w1.y, acc[r].y);
            acc[r].z = fmaf(xv.y, w1.z, acc[r].z);
            acc[r].w = fmaf(xv.y, w1.w, acc[r].w);
            acc[r].x = fmaf(xv.z, w2.x, acc[r].x);
            acc[r].y = fmaf(xv.z, w2.y, acc[r].y);
            acc[r].z = fmaf(xv.z, w2.z, acc[r].z);
            acc[r].w = fmaf(xv.z, w2.w, acc[r].w);
            acc[r].x = fmaf(xv.w, w3.x, acc[r].x);
            acc[r].y = fmaf(xv.w, w3.y, acc[r].y);
            acc[r].z = fmaf(xv.w, w3.z, acc[r].z);
            acc[r].w = fmaf(xv.w, w3.w, acc[r].w);
        }
    }
#pragma unroll
    for (int r = 0; r < 4; ++r) {
        int nd = base + rg * 4 + r;
        float mloc = (cq < 10)
            ? fmaxf(fmaxf(acc[r].x, acc[r].y), fmaxf(acc[r].z, acc[r].w))
            : -INFINITY;
        float m = mloc;
        m = fmaxf(m, __shfl_xor(m, 1));
        m = fmaxf(m, __shfl_xor(m, 2));
        m = fmaxf(m, __shfl_xor(m, 4));
        m = fmaxf(m, __shfl_xor(m, 8));
        float sloc = (cq < 10)
            ? (__expf(acc[r].x - m) + __expf(acc[r].y - m) +
               __expf(acc[r].z - m) + __expf(acc[r].w - m))
            : 0.f;
        float s = sloc;
        s += __shfl_xor(s, 1);
        s += __shfl_xor(s, 2);
        s += __shfl_xor(s, 4);
        s += __shfl_xor(s, 8);
        float ls = m + logf(s);
        if (cq < 10 && nd < N) {
            float4 o;
            o.x = acc[r].x - ls;
            o.y = acc[r].y - ls;
            o.z = acc[r].z - ls;
            o.w = acc[r].w - ls;
            *(float4*)(out + (size_t)nd * NCLASS + cb) = o;
        }
    }
}

// ---------------- launch ----------------

extern "C" void kernel_launch(void* const* d_in, const int* in_sizes, int n_in,
                              void* d_out, int out_size, void* d_ws, size_t ws_size,
                              hipStream_t stream) {
    const float* features = (const float*)d_in[0];
    const int*   erow     = (const int*)d_in[1];
    const int*   ecol     = (const int*)d_in[2];
    const float* eval_    = (const float*)d_in[3];
    const float* Wg       = (const float*)d_in[4];
    const float* att_w    = (const float*)d_in[5];
    const float* att_b    = (const float*)d_in[6];
    const float* fc_w     = (const float*)d_in[7];
    const float* fc_b     = (const float*)d_in[8];
    float*       out      = (float*)d_out;

    // workspace layout (4-byte slots; ~81 MB)
    const size_t SLOTS = (size_t)NF / 2        // tmpb (bf16 spmm result)
                       + 2 * (size_t)NF        // hbb: 4 x NF bf16
                       + (size_t)NF / 2        // fb: NF bf16
                       + 32768                 // Wbt: 4*128*128 bf16
                       + (size_t)EVCAP         // ev (packed u32)
                       + (N + 4)               // rp
                       + N                     // cnt (reused as fs)
                       + 2 * NB                // bsum, boff
                       + 4 * (size_t)N;        // S
    if (ws_size < SLOTS * 4) return;  // readable failure instead of OOB crash

    unsigned short* tmpb = (unsigned short*)d_ws;                // NF bf16
    unsigned short* hbb  = tmpb + (size_t)NF;                    // 4*NF bf16
    unsigned short* fb   = hbb + 4 * (size_t)NF;                 // NF bf16
    unsigned short* Wbt  = fb + (size_t)NF;                      // 65536 bf16
    unsigned*       ev   = (unsigned*)(Wbt + 65536);             // EVCAP u32
    int*            rp   = (int*)(ev + EVCAP);                   // N+1 (+pad)
    int*            cnt  = rp + (N + 4);                         // N (hist/cursor/fs)
    int*            bsum = cnt + N;                              // NB
    int*            boff = bsum + NB;                            // NB
    float*          S    = (float*)(boff + NB);                  // 4*N hop scores
    float*          fs   = (float*)cnt;                          // alias after k_scatter

    // CSR build (rows padded to x4 with packed-zero edges)
    hipMemsetAsync(cnt, 0, N * sizeof(int), stream);
    hipMemsetAsync(ev, 0, EVCAP * sizeof(unsigned), stream);
    k_hist<<<(E + 255) / 256, 256, 0, stream>>>(erow, cnt);
    k_bsum<<<NB, 256, 0, stream>>>(cnt, bsum);
    k_scanb<<<1, 256, 0, stream>>>(bsum, boff);
    k_expand<<<NB, 256, 0, stream>>>(cnt, boff, rp);
    k_scatter<<<(E + 255) / 256, 256, 0, stream>>>(erow, ecol, eval_, cnt, ev);

    // feature score (f32), bf16 feature copy, transposed bf16 weights
    k_fscore<<<(N * 64 + 255) / 256, 256, 0, stream>>>(features, att_w, fs);
    k_cvt<<<(NF / 4 + 255) / 256, 256, 0, stream>>>(features, fb);
    k_cvt_w<<<(NUM_HOPS * NHID * NHID + 255) / 256, 256, 0, stream>>>(Wg, Wbt);

    // hops: spmm (bf16 in/out, f32 acc) -> MFMA gemm (bf16 in/out, f32 acc)
    const unsigned short* xb = fb;
    for (int i = 0; i < NUM_HOPS; ++i) {
        k_spmm<<<(N / 4) * 64 / 256, 256, 0, stream>>>(rp, ev, xb, tmpb);
        k_gemm<<<(N + 63) / 64, 256, 0, stream>>>(tmpb, Wbt + (size_t)i * NHID * NHID,
                                                  att_w, hbb + (size_t)i * NF,
                                                  S + (size_t)i * N);
        xb = hbb + (size_t)i * NF;
    }

    // attention + fc + log_softmax (bf16 h input, f32 math)
    k_attn_final<<<(N + 63) / 64, 256, 0, stream>>>(hbb, S, fs, att_b, fc_w, fc_b, out);
}